// Round 1
// baseline (269.682 us; speedup 1.0000x reference)
//
#include <hip/hip_runtime.h>
#include <math.h>

#define NMEL   40
#define NCEP   13
#define BATCH  1024
#define NSAMP  16000
#define NFRAME 49
#define PI_F   3.14159265358979323846f

// d_ws float layout
#define WS_WIN  0        // 640 floats: Hann window
#define WS_R    640      // 512 float2: W_1024^k, k=0..511 (1024 floats)
#define WS_DT   1664     // 520 floats: DCT * 1/sqrt(80) * lifter, [40][13]
#define WS_BT   2184     // f16 area: Bt[48][544] mel weights transposed (13056 floats)
#define WS_TOT  15240

typedef _Float16 half8 __attribute__((ext_vector_type(8)));
typedef __fp16   fp16x2 __attribute__((ext_vector_type(2)));
typedef float f32x4 __attribute__((ext_vector_type(4)));

// r11: DS-only scheduling fence. The old WAVE_FENCE (asm ::: "memory") was a
// compiler memory barrier: it drained vmcnt (so the per-frame global sample
// loads could never be prefetched across a fence) and pinned all VALU into
// strict phase order. A wave's DS ops execute in HW order; correctness only
// needs the compiler to preserve DS *program order*, which sched_barrier
// gives us directly: mask 0x77 = ALU|VALU|SALU|VMEM(all) may cross, DS bits
// (0x80/0x100/0x200) unset -> no ds_* crosses. Emits no instruction.
#define FFT_SB() __builtin_amdgcn_sched_barrier(0x77)

// radix-2 DIF butterfly on register arrays
#define BFLY(i0, i1, wr, wi) {                        \
    float tr = zr[i0] - zr[i1], ti = zi[i0] - zi[i1]; \
    zr[i0] += zr[i1]; zi[i0] += zi[i1];               \
    zr[i1] = tr*(wr) - ti*(wi);                       \
    zi[i1] = tr*(wi) + ti*(wr); }

__device__ __forceinline__ unsigned pk_f16(float a, float b) {
    fp16x2 h = __builtin_amdgcn_cvt_pkrtz(a, b);
    union { fp16x2 h; unsigned u; } cvt; cvt.h = h;
    return cvt.u;
}

// ---------------------------------------------------------------------------
// Prep: window / twiddle / DCT tables + transposed, padded f16 mel weights.
// ---------------------------------------------------------------------------
__global__ __launch_bounds__(256) void mfcc_prep(
    const float* __restrict__ mel_fb, float* __restrict__ ws)
{
    const int idx = blockIdx.x * 256 + threadIdx.x;   // grid = 64 blocks

    _Float16* bt = (_Float16*)(ws + WS_BT);
    for (int i = idx; i < 48 * 544; i += 64 * 256) {
        int n = i / 544, k = i - n * 544;
        float v = (n < NMEL && k < 513) ? mel_fb[k * NMEL + n] : 0.0f;
        bt[i] = (_Float16)v;
    }

    if (idx < 640 + 512 + 520) {
        int i = idx;
        if (i < 640) {
            ws[WS_WIN + i] = 0.5f - 0.5f * cosf(2.0f * PI_F * (float)i / 640.0f);
        } else if (i < 1152) {
            int k = i - 640;
            float s, c;
            sincosf(-2.0f * PI_F * (float)k / 1024.0f, &s, &c);
            ((float2*)(ws + WS_R))[k] = make_float2(c, s);
        } else {
            int j = i - 1152;
            int m = j / 13, c0 = j - m * 13;
            float d    = 2.0f * cosf(PI_F * (2.0f * m + 1.0f) * (float)c0 / 80.0f);
            float lift = 1.0f + 11.0f * sinf(PI_F * (float)c0 / 22.0f);
            ws[WS_DT + j] = d * 0.11180339887498949f * lift;   // 1/sqrt(80)
        }
    }
}

// ---------------------------------------------------------------------------
// Stage 1: 16 frames per block (4 waves x 4 sequential FFTs).
// r10: all LDS phases use slot(x) = x + 2*(x>>3) padding; writes <=2-way-
// conflict-free, reads lane-contiguous 16B-aligned ds_read_b128.
// r11: latency-serialization fix — DS-only sched_barrier fences (VALU/VMEM
// permeable) + 1-frame-ahead prefetch of the sample loads. launch_bounds
// min-waves=5 holds the allocator at the 96-VGPR granule so the +10 prefetch
// registers don't cost a wave of residency.
// ---------------------------------------------------------------------------
__global__ __launch_bounds__(256, 5) void mfcc_stage1(
    const float* __restrict__ wave, const float* __restrict__ ws,
    float* __restrict__ out)
{
    // LDS: float2 Z[4][640] overlaid by f16 mag[16][552]; + f16 lm[16][40]
    __shared__ __align__(16) char smem[4 * 640 * 8 + 16 * 40 * 2];
    char* smemc = smem;
    _Float16* lm = (_Float16*)(smem + 4 * 640 * 8);  // [16][40] f16

    const int tid = threadIdx.x;
    const int wv  = tid >> 6;
    const int L   = tid & 63;
    const int s   = L & 7;
    const int a   = L >> 3;

    float2* Z = (float2*)smem + wv * 640;            // wave-private FFT buffer
    const float2* R   = (const float2*)(ws + WS_R);
    const float2* win = (const float2*)(ws + WS_WIN);

    // ---- hoist all loop-invariant tables into registers (once per wave) ----
    float2 twA[4], twB[2], twC, twD[4], twE[2], twF, twS[8], winv[5];
    #pragma unroll
    for (int j = 0; j < 4; ++j) twA[j] = R[2 * (L + 64 * j)];
    #pragma unroll
    for (int j = 0; j < 2; ++j) twB[j] = R[4 * (L + 64 * j)];
    twC = R[8 * L];
    #pragma unroll
    for (int j = 0; j < 4; ++j) twD[j] = R[128 * j + 16 * s];
    #pragma unroll
    for (int j = 0; j < 2; ++j) twE[j] = R[256 * j + 32 * s];
    twF = R[64 * s];
    #pragma unroll
    for (int j = 0; j < 8; ++j) twS[j] = R[8 * L + j];   // real-split W_1024^k
    #pragma unroll
    for (int j = 0; j < 5; ++j) winv[j] = win[L + 64 * j];

    uint4 mgp[4];          // per-frame packed f16 magnitudes (8 per lane)
    float m512v[4] = {0.0f, 0.0f, 0.0f, 0.0f};

    // r11: prefetch frame 0's samples
    float2 xv[5];
    {
        const int frame = blockIdx.x * 16 + wv * 4;
        const int b = frame / NFRAME;
        const int f = frame - b * NFRAME;
        const float2* xp = (const float2*)(wave + (size_t)b * NSAMP + (size_t)f * 320);
        #pragma unroll
        for (int j = 0; j < 5; ++j) xv[j] = xp[L + 64 * j];
    }

    #pragma unroll
    for (int fi = 0; fi < 4; ++fi) {
        // r11: issue NEXT frame's 5 global loads now; their HBM latency
        // hides under this frame's entire FFT (fences are VMEM-permeable).
        float2 xn[5];
        if (fi < 3) {
            const int frame = blockIdx.x * 16 + wv * 4 + fi + 1;
            const int b = frame / NFRAME;
            const int f = frame - b * NFRAME;
            const float2* xp = (const float2*)(wave + (size_t)b * NSAMP + (size_t)f * 320);
            #pragma unroll
            for (int j = 0; j < 5; ++j) xn[j] = xp[L + 64 * j];
        }

        float zr[8], zi[8];
        #pragma unroll
        for (int j = 0; j < 8; ++j) { zr[j] = 0.0f; zi[j] = 0.0f; }
        // z[n] = x[2n]*w[2n] + i*x[2n+1]*w[2n+1], n = L + 64j (nonzero j<5)
        #pragma unroll
        for (int j = 0; j < 5; ++j) {
            zr[j] = xv[j].x * winv[j].x;
            zi[j] = xv[j].y * winv[j].y;
        }

        // ---- register stages on coset n = L + 64j ----
        #pragma unroll
        for (int j = 0; j < 4; ++j) BFLY(j, j + 4, twA[j].x, twA[j].y);   // 512
        #pragma unroll
        for (int g = 0; g < 8; g += 4) {                                  // 256
            #pragma unroll
            for (int j = 0; j < 2; ++j) BFLY(g + j, g + j + 2, twB[j].x, twB[j].y);
        }
        #pragma unroll
        for (int i0 = 0; i0 < 8; i0 += 2) BFLY(i0, i0 + 1, twC.x, twC.y); // 128

        // ---- exchange 1 (swapped): element n=L+64j -> slot 80j+10s+a;
        //      read lane-contiguous slots 10L+j as 2x b128 ----
        FFT_SB();
        #pragma unroll
        for (int j = 0; j < 8; ++j)
            Z[80 * j + 10 * s + a] = make_float2(zr[j], zi[j]);
        FFT_SB();
        {
            float4 q0 = *(float4*)&Z[10 * L + 0];
            float4 q1 = *(float4*)&Z[10 * L + 2];
            float4 q2 = *(float4*)&Z[10 * L + 4];
            float4 q3 = *(float4*)&Z[10 * L + 6];
            zr[0] = q0.x; zi[0] = q0.y; zr[1] = q0.z; zi[1] = q0.w;
            zr[2] = q1.x; zi[2] = q1.y; zr[3] = q1.z; zi[3] = q1.w;
            zr[4] = q2.x; zi[4] = q2.y; zr[5] = q2.z; zi[5] = q2.w;
            zr[6] = q3.x; zi[6] = q3.y; zr[7] = q3.z; zi[7] = q3.w;
        }
        // now lane L holds n = 64*(L>>3) + 8j + s (same as before)

        // ---- register stages on coset q = 8j + s within 64-blocks ----
        #pragma unroll
        for (int j = 0; j < 4; ++j) BFLY(j, j + 4, twD[j].x, twD[j].y);   // 64
        #pragma unroll
        for (int g = 0; g < 8; g += 4) {                                  // 32
            #pragma unroll
            for (int j = 0; j < 2; ++j) BFLY(g + j, g + j + 2, twE[j].x, twE[j].y);
        }
        #pragma unroll
        for (int i0 = 0; i0 < 8; i0 += 2) BFLY(i0, i0 + 1, twF.x, twF.y); // 16

        // ---- exchange 2: element n=64a+8j+s -> slot(n) = 80a+10j+s;
        //      read slots 10L+j (= slot(8L+j)) as 2x b128 ----
        FFT_SB();
        #pragma unroll
        for (int j = 0; j < 8; ++j)
            Z[80 * a + 10 * j + s] = make_float2(zr[j], zi[j]);
        FFT_SB();
        {
            float4 q0 = *(float4*)&Z[10 * L + 0];
            float4 q1 = *(float4*)&Z[10 * L + 2];
            float4 q2 = *(float4*)&Z[10 * L + 4];
            float4 q3 = *(float4*)&Z[10 * L + 6];
            zr[0] = q0.x; zi[0] = q0.y; zr[1] = q0.z; zi[1] = q0.w;
            zr[2] = q1.x; zi[2] = q1.y; zr[3] = q1.z; zi[3] = q1.w;
            zr[4] = q2.x; zi[4] = q2.y; zr[5] = q2.z; zi[5] = q2.w;
            zr[6] = q3.x; zi[6] = q3.y; zr[7] = q3.z; zi[7] = q3.w;
        }

        // ---- register stages on q = j (size 8,4,2) ----
        {
            const float C = 0.70710678118654752f;
            const float w8r[4] = { 1.0f,  C, 0.0f, -C };
            const float w8i[4] = { 0.0f, -C, -1.0f, -C };
            #pragma unroll
            for (int j = 0; j < 4; ++j) BFLY(j, j + 4, w8r[j], w8i[j]);
            #pragma unroll
            for (int g = 0; g < 8; g += 4) {
                BFLY(g + 0, g + 2, 1.0f, 0.0f);
                BFLY(g + 1, g + 3, 0.0f, -1.0f);
            }
            #pragma unroll
            for (int i0 = 0; i0 < 8; i0 += 2) BFLY(i0, i0 + 1, 1.0f, 0.0f);
        }

        // ---- write X[k] at slot(k), k = rev3(j)*64 + rev6(L) ----
        FFT_SB();
        {
            const int rev3t[8] = { 0, 4, 2, 6, 1, 5, 3, 7 };
            int r6 = (int)(__brev((unsigned)L) >> 26);
            int u  = r6 + 2 * (r6 >> 3);
            #pragma unroll
            for (int j = 0; j < 8; ++j)
                Z[80 * rev3t[j] + u] = make_float2(zr[j], zi[j]);
        }
        FFT_SB();

        // ---- real-split + |X|, k = 8L+j. A-side slot(k)=10L+j (2x b128);
        //      B-side slot(512-k)=638-10L-j for j>=1 (2x b128 window), j=0 at
        //      640-10L (b64). ----
        float Ax[8], Ay[8], Bx[8], By[8];
        {
            float4 a0 = *(float4*)&Z[10 * L + 0];
            float4 a1 = *(float4*)&Z[10 * L + 2];
            float4 a2 = *(float4*)&Z[10 * L + 4];
            float4 a3 = *(float4*)&Z[10 * L + 6];
            Ax[0] = a0.x; Ay[0] = a0.y; Ax[1] = a0.z; Ay[1] = a0.w;
            Ax[2] = a1.x; Ay[2] = a1.y; Ax[3] = a1.z; Ay[3] = a1.w;
            Ax[4] = a2.x; Ay[4] = a2.y; Ax[5] = a2.z; Ay[5] = a2.w;
            Ax[6] = a3.x; Ay[6] = a3.y; Ax[7] = a3.z; Ay[7] = a3.w;
            float4 t0 = *(float4*)&Z[630 - 10 * L + 0];   // i=0,1 (j=8,7)
            float4 t1 = *(float4*)&Z[630 - 10 * L + 2];   // i=2,3 (j=6,5)
            float4 t2 = *(float4*)&Z[630 - 10 * L + 4];   // i=4,5 (j=4,3)
            float4 t3 = *(float4*)&Z[630 - 10 * L + 6];   // i=6,7 (j=2,1)
            float2 b0 = Z[640 - 10 * L];                  // j=0 (garbage if L==0)
            Bx[0] = b0.x;  By[0] = b0.y;
            Bx[7] = t0.z;  By[7] = t0.w;
            Bx[6] = t1.x;  By[6] = t1.y;
            Bx[5] = t1.z;  By[5] = t1.w;
            Bx[4] = t2.x;  By[4] = t2.y;
            Bx[3] = t2.z;  By[3] = t2.w;
            Bx[2] = t3.x;  By[2] = t3.y;
            Bx[1] = t3.z;  By[1] = t3.w;
        }
        float mg[8];
        #pragma unroll
        for (int j = 0; j < 8; ++j) {
            int k = 8 * L + j;
            if (k == 0) {                    // lane 0, j 0 only
                mg[j]     = fabsf(Ax[0] + Ay[0]);
                m512v[fi] = fabsf(Ax[0] - Ay[0]);
            } else {
                float xer = 0.5f * (Ax[j] + Bx[j]), xei = 0.5f * (Ay[j] - By[j]);
                float xo  = 0.5f * (Ay[j] + By[j]), xoi = -0.5f * (Ax[j] - Bx[j]);
                float xr = xer + twS[j].x * xo - twS[j].y * xoi;
                float xi = xei + twS[j].x * xoi + twS[j].y * xo;
                mg[j] = sqrtf(xr * xr + xi * xi);
            }
        }
        mgp[fi].x = pk_f16(mg[0], mg[1]);
        mgp[fi].y = pk_f16(mg[2], mg[3]);
        mgp[fi].z = pk_f16(mg[4], mg[5]);
        mgp[fi].w = pk_f16(mg[6], mg[7]);
        FFT_SB();  // Z reads ordered before next frame's writes

        if (fi < 3) {
            #pragma unroll
            for (int j = 0; j < 5; ++j) xv[j] = xn[j];
        }
    }

    // ---- all FFTs done: overlay mag tile [16][552] f16 onto smem ----
    __syncthreads();
    #pragma unroll
    for (int fi = 0; fi < 4; ++fi) {
        const int row = wv * 4 + fi;
        *(uint4*)(smemc + row * 1104 + 16 * L) = mgp[fi];
        if (L < 20) {   // zero pad bins [512..552), bin 512 = m512
            unsigned v = (L == 0) ? pk_f16(m512v[fi], 0.0f) : 0u;
            *(unsigned*)(smemc + row * 1104 + 1024 + 4 * L) = v;
        }
    }
    __syncthreads();

    // ---- mel projection: D[16 frames][16 mels] per wave, K = 544 ----
    if (wv < 3) {
        const int nl = L & 15, q = L >> 4;
        const char* ap = smemc + nl * 1104 + q * 16;                // A: frame rows
        const _Float16* btp = (const _Float16*)(ws + WS_BT)
                              + (size_t)(wv * 16 + nl) * 544 + q * 8;
        f32x4 acc = {0.0f, 0.0f, 0.0f, 0.0f};
        #pragma unroll
        for (int kk = 0; kk < 17; ++kk) {
            half8 av = *(const half8*)(ap + kk * 64);
            half8 bv = *(const half8*)(btp + kk * 32);
            acc = __builtin_amdgcn_mfma_f32_16x16x32_f16(av, bv, acc, 0, 0, 0);
        }
        const int mel = wv * 16 + nl;
        if (mel < NMEL) {
            #pragma unroll
            for (int r = 0; r < 4; ++r) {
                int fl = q * 4 + r;                 // C/D: row=(lane>>4)*4+r
                lm[fl * NMEL + mel] = (_Float16)__logf(acc[r] + 1e-6f);
            }
        }
    }
    __syncthreads();

    // ---- DCT + scale + lifter, fp32: 208 threads = 16 frames x 13 ceps ----
    if (tid < 16 * NCEP) {
        const int fl = tid / NCEP, c = tid - fl * NCEP;
        float acc = 0.0f;
        #pragma unroll
        for (int m = 0; m < NMEL; ++m)
            acc += (float)lm[fl * NMEL + m] * ws[WS_DT + m * 13 + c];
        out[(size_t)(blockIdx.x * 16 + fl) * (3 * NCEP) + c] = acc;
    }
}

// ---------------------------------------------------------------------------
// Stage 2: per-batch deltas.
// ---------------------------------------------------------------------------
__global__ __launch_bounds__(128) void mfcc_stage2(float* __restrict__ out)
{
    __shared__ float x [NFRAME * NCEP];
    __shared__ float d1[NFRAME * NCEP];

    const int b = blockIdx.x;
    const int tid = threadIdx.x;
    const int TC = NFRAME * NCEP;

    for (int i = tid; i < TC; i += 128) {
        const int t = i / NCEP, c = i - t * NCEP;
        x[i] = out[((size_t)b * NFRAME + t) * (3 * NCEP) + c];
    }
    __syncthreads();

    for (int i = tid; i < TC; i += 128) {
        const int t = i / NCEP, c = i - t * NCEP;
        float acc = 0.0f;
        #pragma unroll
        for (int k = -2; k <= 2; ++k) {
            if (k == 0) continue;
            int tt = t + k;
            tt = tt < 0 ? 0 : (tt > NFRAME - 1 ? NFRAME - 1 : tt);
            acc += (float)k * x[tt * NCEP + c];
        }
        d1[i] = acc * 0.1f;
    }
    __syncthreads();

    for (int i = tid; i < TC; i += 128) {
        const int t = i / NCEP, c = i - t * NCEP;
        float acc = 0.0f;
        #pragma unroll
        for (int k = -2; k <= 2; ++k) {
            if (k == 0) continue;
            int tt = t + k;
            tt = tt < 0 ? 0 : (tt > NFRAME - 1 ? NFRAME - 1 : tt);
            acc += (float)k * d1[tt * NCEP + c];
        }
        const size_t base = ((size_t)b * NFRAME + t) * (3 * NCEP);
        out[base +     NCEP + c] = d1[i];
        out[base + 2 * NCEP + c] = acc * 0.1f;
    }
}

extern "C" void kernel_launch(void* const* d_in, const int* in_sizes, int n_in,
                              void* d_out, int out_size, void* d_ws, size_t ws_size,
                              hipStream_t stream)
{
    const float* wave   = (const float*)d_in[0];   // [1024][16000] f32
    const float* mel_fb = (const float*)d_in[1];   // [513][40] f32
    float* out = (float*)d_out;                    // [1024][49][39][1] f32
    float* ws  = (float*)d_ws;

    mfcc_prep<<<64, 256, 0, stream>>>(mel_fb, ws);
    mfcc_stage1<<<(BATCH * NFRAME) / 16, 256, 0, stream>>>(wave, ws, out);
    mfcc_stage2<<<BATCH, 128, 0, stream>>>(out);
}

// Round 2
// 168.385 us; speedup vs baseline: 1.6016x; 1.6016x over previous
//
#include <hip/hip_runtime.h>
#include <math.h>

#define NMEL   40
#define NCEP   13
#define BATCH  1024
#define NSAMP  16000
#define NFRAME 49
#define PI_F   3.14159265358979323846f

// d_ws float layout
#define WS_WIN  0        // 640 floats: Hann window
#define WS_R    640      // 512 float2: W_1024^k, k=0..511 (1024 floats)
#define WS_DT   1664     // 520 floats: DCT * 1/sqrt(80) * lifter, [40][13]
#define WS_BT   2184     // f16 area: Bt[48][544] mel weights transposed (13056 floats)
#define WS_TOT  15240

typedef _Float16 half8 __attribute__((ext_vector_type(8)));
typedef __fp16   fp16x2 __attribute__((ext_vector_type(2)));
typedef float f32x4 __attribute__((ext_vector_type(4)));

// r11: DS-only scheduling fence (no instruction emitted, VMEM/VALU permeable).
// mask 0x77 = ALU|VALU|SALU|VMEM may cross; DS bits unset -> ds_* stay ordered.
// r12: KEPT. r11's regression was the __launch_bounds__ min-waves clamp
// (VGPR 92->48, spill traffic 211+295 GB), not the fences. Reverted to plain
// __launch_bounds__(256): the FFT's ~100-VGPR working set is a hard floor —
// never buy occupancy with spills.
#define FFT_SB() __builtin_amdgcn_sched_barrier(0x77)

// radix-2 DIF butterfly on register arrays
#define BFLY(i0, i1, wr, wi) {                        \
    float tr = zr[i0] - zr[i1], ti = zi[i0] - zi[i1]; \
    zr[i0] += zr[i1]; zi[i0] += zi[i1];               \
    zr[i1] = tr*(wr) - ti*(wi);                       \
    zi[i1] = tr*(wi) + ti*(wr); }

__device__ __forceinline__ unsigned pk_f16(float a, float b) {
    fp16x2 h = __builtin_amdgcn_cvt_pkrtz(a, b);
    union { fp16x2 h; unsigned u; } cvt; cvt.h = h;
    return cvt.u;
}

// ---------------------------------------------------------------------------
// Prep: window / twiddle / DCT tables + transposed, padded f16 mel weights.
// ---------------------------------------------------------------------------
__global__ __launch_bounds__(256) void mfcc_prep(
    const float* __restrict__ mel_fb, float* __restrict__ ws)
{
    const int idx = blockIdx.x * 256 + threadIdx.x;   // grid = 64 blocks

    _Float16* bt = (_Float16*)(ws + WS_BT);
    for (int i = idx; i < 48 * 544; i += 64 * 256) {
        int n = i / 544, k = i - n * 544;
        float v = (n < NMEL && k < 513) ? mel_fb[k * NMEL + n] : 0.0f;
        bt[i] = (_Float16)v;
    }

    if (idx < 640 + 512 + 520) {
        int i = idx;
        if (i < 640) {
            ws[WS_WIN + i] = 0.5f - 0.5f * cosf(2.0f * PI_F * (float)i / 640.0f);
        } else if (i < 1152) {
            int k = i - 640;
            float s, c;
            sincosf(-2.0f * PI_F * (float)k / 1024.0f, &s, &c);
            ((float2*)(ws + WS_R))[k] = make_float2(c, s);
        } else {
            int j = i - 1152;
            int m = j / 13, c0 = j - m * 13;
            float d    = 2.0f * cosf(PI_F * (2.0f * m + 1.0f) * (float)c0 / 80.0f);
            float lift = 1.0f + 11.0f * sinf(PI_F * (float)c0 / 22.0f);
            ws[WS_DT + j] = d * 0.11180339887498949f * lift;   // 1/sqrt(80)
        }
    }
}

// ---------------------------------------------------------------------------
// Stage 1: 16 frames per block (4 waves x 4 sequential FFTs).
// r10: all LDS phases use slot(x) = x + 2*(x>>3) padding; writes <=2-way-
// conflict-free, reads lane-contiguous 16B-aligned ds_read_b128.
// r11: DS-only sched_barrier fences + 1-frame-ahead sample prefetch.
// r12: plain __launch_bounds__(256) — no min-wave clamp (r11 post-mortem).
// ---------------------------------------------------------------------------
__global__ __launch_bounds__(256) void mfcc_stage1(
    const float* __restrict__ wave, const float* __restrict__ ws,
    float* __restrict__ out)
{
    // LDS: float2 Z[4][640] overlaid by f16 mag[16][552]; + f16 lm[16][40]
    __shared__ __align__(16) char smem[4 * 640 * 8 + 16 * 40 * 2];
    char* smemc = smem;
    _Float16* lm = (_Float16*)(smem + 4 * 640 * 8);  // [16][40] f16

    const int tid = threadIdx.x;
    const int wv  = tid >> 6;
    const int L   = tid & 63;
    const int s   = L & 7;
    const int a   = L >> 3;

    float2* Z = (float2*)smem + wv * 640;            // wave-private FFT buffer
    const float2* R   = (const float2*)(ws + WS_R);
    const float2* win = (const float2*)(ws + WS_WIN);

    // ---- hoist all loop-invariant tables into registers (once per wave) ----
    float2 twA[4], twB[2], twC, twD[4], twE[2], twF, twS[8], winv[5];
    #pragma unroll
    for (int j = 0; j < 4; ++j) twA[j] = R[2 * (L + 64 * j)];
    #pragma unroll
    for (int j = 0; j < 2; ++j) twB[j] = R[4 * (L + 64 * j)];
    twC = R[8 * L];
    #pragma unroll
    for (int j = 0; j < 4; ++j) twD[j] = R[128 * j + 16 * s];
    #pragma unroll
    for (int j = 0; j < 2; ++j) twE[j] = R[256 * j + 32 * s];
    twF = R[64 * s];
    #pragma unroll
    for (int j = 0; j < 8; ++j) twS[j] = R[8 * L + j];   // real-split W_1024^k
    #pragma unroll
    for (int j = 0; j < 5; ++j) winv[j] = win[L + 64 * j];

    uint4 mgp[4];          // per-frame packed f16 magnitudes (8 per lane)
    float m512v[4] = {0.0f, 0.0f, 0.0f, 0.0f};

    // r11: prefetch frame 0's samples
    float2 xv[5];
    {
        const int frame = blockIdx.x * 16 + wv * 4;
        const int b = frame / NFRAME;
        const int f = frame - b * NFRAME;
        const float2* xp = (const float2*)(wave + (size_t)b * NSAMP + (size_t)f * 320);
        #pragma unroll
        for (int j = 0; j < 5; ++j) xv[j] = xp[L + 64 * j];
    }

    #pragma unroll
    for (int fi = 0; fi < 4; ++fi) {
        // r11: issue NEXT frame's 5 global loads now; their HBM latency
        // hides under this frame's entire FFT (fences are VMEM-permeable).
        float2 xn[5];
        if (fi < 3) {
            const int frame = blockIdx.x * 16 + wv * 4 + fi + 1;
            const int b = frame / NFRAME;
            const int f = frame - b * NFRAME;
            const float2* xp = (const float2*)(wave + (size_t)b * NSAMP + (size_t)f * 320);
            #pragma unroll
            for (int j = 0; j < 5; ++j) xn[j] = xp[L + 64 * j];
        }

        float zr[8], zi[8];
        #pragma unroll
        for (int j = 0; j < 8; ++j) { zr[j] = 0.0f; zi[j] = 0.0f; }
        // z[n] = x[2n]*w[2n] + i*x[2n+1]*w[2n+1], n = L + 64j (nonzero j<5)
        #pragma unroll
        for (int j = 0; j < 5; ++j) {
            zr[j] = xv[j].x * winv[j].x;
            zi[j] = xv[j].y * winv[j].y;
        }

        // ---- register stages on coset n = L + 64j ----
        #pragma unroll
        for (int j = 0; j < 4; ++j) BFLY(j, j + 4, twA[j].x, twA[j].y);   // 512
        #pragma unroll
        for (int g = 0; g < 8; g += 4) {                                  // 256
            #pragma unroll
            for (int j = 0; j < 2; ++j) BFLY(g + j, g + j + 2, twB[j].x, twB[j].y);
        }
        #pragma unroll
        for (int i0 = 0; i0 < 8; i0 += 2) BFLY(i0, i0 + 1, twC.x, twC.y); // 128

        // ---- exchange 1 (swapped): element n=L+64j -> slot 80j+10s+a;
        //      read lane-contiguous slots 10L+j as 2x b128 ----
        FFT_SB();
        #pragma unroll
        for (int j = 0; j < 8; ++j)
            Z[80 * j + 10 * s + a] = make_float2(zr[j], zi[j]);
        FFT_SB();
        {
            float4 q0 = *(float4*)&Z[10 * L + 0];
            float4 q1 = *(float4*)&Z[10 * L + 2];
            float4 q2 = *(float4*)&Z[10 * L + 4];
            float4 q3 = *(float4*)&Z[10 * L + 6];
            zr[0] = q0.x; zi[0] = q0.y; zr[1] = q0.z; zi[1] = q0.w;
            zr[2] = q1.x; zi[2] = q1.y; zr[3] = q1.z; zi[3] = q1.w;
            zr[4] = q2.x; zi[4] = q2.y; zr[5] = q2.z; zi[5] = q2.w;
            zr[6] = q3.x; zi[6] = q3.y; zr[7] = q3.z; zi[7] = q3.w;
        }
        // now lane L holds n = 64*(L>>3) + 8j + s (same as before)

        // ---- register stages on coset q = 8j + s within 64-blocks ----
        #pragma unroll
        for (int j = 0; j < 4; ++j) BFLY(j, j + 4, twD[j].x, twD[j].y);   // 64
        #pragma unroll
        for (int g = 0; g < 8; g += 4) {                                  // 32
            #pragma unroll
            for (int j = 0; j < 2; ++j) BFLY(g + j, g + j + 2, twE[j].x, twE[j].y);
        }
        #pragma unroll
        for (int i0 = 0; i0 < 8; i0 += 2) BFLY(i0, i0 + 1, twF.x, twF.y); // 16

        // ---- exchange 2: element n=64a+8j+s -> slot(n) = 80a+10j+s;
        //      read slots 10L+j (= slot(8L+j)) as 2x b128 ----
        FFT_SB();
        #pragma unroll
        for (int j = 0; j < 8; ++j)
            Z[80 * a + 10 * j + s] = make_float2(zr[j], zi[j]);
        FFT_SB();
        {
            float4 q0 = *(float4*)&Z[10 * L + 0];
            float4 q1 = *(float4*)&Z[10 * L + 2];
            float4 q2 = *(float4*)&Z[10 * L + 4];
            float4 q3 = *(float4*)&Z[10 * L + 6];
            zr[0] = q0.x; zi[0] = q0.y; zr[1] = q0.z; zi[1] = q0.w;
            zr[2] = q1.x; zi[2] = q1.y; zr[3] = q1.z; zi[3] = q1.w;
            zr[4] = q2.x; zi[4] = q2.y; zr[5] = q2.z; zi[5] = q2.w;
            zr[6] = q3.x; zi[6] = q3.y; zr[7] = q3.z; zi[7] = q3.w;
        }

        // ---- register stages on q = j (size 8,4,2) ----
        {
            const float C = 0.70710678118654752f;
            const float w8r[4] = { 1.0f,  C, 0.0f, -C };
            const float w8i[4] = { 0.0f, -C, -1.0f, -C };
            #pragma unroll
            for (int j = 0; j < 4; ++j) BFLY(j, j + 4, w8r[j], w8i[j]);
            #pragma unroll
            for (int g = 0; g < 8; g += 4) {
                BFLY(g + 0, g + 2, 1.0f, 0.0f);
                BFLY(g + 1, g + 3, 0.0f, -1.0f);
            }
            #pragma unroll
            for (int i0 = 0; i0 < 8; i0 += 2) BFLY(i0, i0 + 1, 1.0f, 0.0f);
        }

        // ---- write X[k] at slot(k), k = rev3(j)*64 + rev6(L) ----
        FFT_SB();
        {
            const int rev3t[8] = { 0, 4, 2, 6, 1, 5, 3, 7 };
            int r6 = (int)(__brev((unsigned)L) >> 26);
            int u  = r6 + 2 * (r6 >> 3);
            #pragma unroll
            for (int j = 0; j < 8; ++j)
                Z[80 * rev3t[j] + u] = make_float2(zr[j], zi[j]);
        }
        FFT_SB();

        // ---- real-split + |X|, k = 8L+j. A-side slot(k)=10L+j (2x b128);
        //      B-side slot(512-k)=638-10L-j for j>=1 (2x b128 window), j=0 at
        //      640-10L (b64). ----
        float Ax[8], Ay[8], Bx[8], By[8];
        {
            float4 a0 = *(float4*)&Z[10 * L + 0];
            float4 a1 = *(float4*)&Z[10 * L + 2];
            float4 a2 = *(float4*)&Z[10 * L + 4];
            float4 a3 = *(float4*)&Z[10 * L + 6];
            Ax[0] = a0.x; Ay[0] = a0.y; Ax[1] = a0.z; Ay[1] = a0.w;
            Ax[2] = a1.x; Ay[2] = a1.y; Ax[3] = a1.z; Ay[3] = a1.w;
            Ax[4] = a2.x; Ay[4] = a2.y; Ax[5] = a2.z; Ay[5] = a2.w;
            Ax[6] = a3.x; Ay[6] = a3.y; Ax[7] = a3.z; Ay[7] = a3.w;
            float4 t0 = *(float4*)&Z[630 - 10 * L + 0];   // i=0,1 (j=8,7)
            float4 t1 = *(float4*)&Z[630 - 10 * L + 2];   // i=2,3 (j=6,5)
            float4 t2 = *(float4*)&Z[630 - 10 * L + 4];   // i=4,5 (j=4,3)
            float4 t3 = *(float4*)&Z[630 - 10 * L + 6];   // i=6,7 (j=2,1)
            float2 b0 = Z[640 - 10 * L];                  // j=0 (garbage if L==0)
            Bx[0] = b0.x;  By[0] = b0.y;
            Bx[7] = t0.z;  By[7] = t0.w;
            Bx[6] = t1.x;  By[6] = t1.y;
            Bx[5] = t1.z;  By[5] = t1.w;
            Bx[4] = t2.x;  By[4] = t2.y;
            Bx[3] = t2.z;  By[3] = t2.w;
            Bx[2] = t3.x;  By[2] = t3.y;
            Bx[1] = t3.z;  By[1] = t3.w;
        }
        float mg[8];
        #pragma unroll
        for (int j = 0; j < 8; ++j) {
            int k = 8 * L + j;
            if (k == 0) {                    // lane 0, j 0 only
                mg[j]     = fabsf(Ax[0] + Ay[0]);
                m512v[fi] = fabsf(Ax[0] - Ay[0]);
            } else {
                float xer = 0.5f * (Ax[j] + Bx[j]), xei = 0.5f * (Ay[j] - By[j]);
                float xo  = 0.5f * (Ay[j] + By[j]), xoi = -0.5f * (Ax[j] - Bx[j]);
                float xr = xer + twS[j].x * xo - twS[j].y * xoi;
                float xi = xei + twS[j].x * xoi + twS[j].y * xo;
                mg[j] = sqrtf(xr * xr + xi * xi);
            }
        }
        mgp[fi].x = pk_f16(mg[0], mg[1]);
        mgp[fi].y = pk_f16(mg[2], mg[3]);
        mgp[fi].z = pk_f16(mg[4], mg[5]);
        mgp[fi].w = pk_f16(mg[6], mg[7]);
        FFT_SB();  // Z reads ordered before next frame's writes

        if (fi < 3) {
            #pragma unroll
            for (int j = 0; j < 5; ++j) xv[j] = xn[j];
        }
    }

    // ---- all FFTs done: overlay mag tile [16][552] f16 onto smem ----
    __syncthreads();
    #pragma unroll
    for (int fi = 0; fi < 4; ++fi) {
        const int row = wv * 4 + fi;
        *(uint4*)(smemc + row * 1104 + 16 * L) = mgp[fi];
        if (L < 20) {   // zero pad bins [512..552), bin 512 = m512
            unsigned v = (L == 0) ? pk_f16(m512v[fi], 0.0f) : 0u;
            *(unsigned*)(smemc + row * 1104 + 1024 + 4 * L) = v;
        }
    }
    __syncthreads();

    // ---- mel projection: D[16 frames][16 mels] per wave, K = 544 ----
    if (wv < 3) {
        const int nl = L & 15, q = L >> 4;
        const char* ap = smemc + nl * 1104 + q * 16;                // A: frame rows
        const _Float16* btp = (const _Float16*)(ws + WS_BT)
                              + (size_t)(wv * 16 + nl) * 544 + q * 8;
        f32x4 acc = {0.0f, 0.0f, 0.0f, 0.0f};
        #pragma unroll
        for (int kk = 0; kk < 17; ++kk) {
            half8 av = *(const half8*)(ap + kk * 64);
            half8 bv = *(const half8*)(btp + kk * 32);
            acc = __builtin_amdgcn_mfma_f32_16x16x32_f16(av, bv, acc, 0, 0, 0);
        }
        const int mel = wv * 16 + nl;
        if (mel < NMEL) {
            #pragma unroll
            for (int r = 0; r < 4; ++r) {
                int fl = q * 4 + r;                 // C/D: row=(lane>>4)*4+r
                lm[fl * NMEL + mel] = (_Float16)__logf(acc[r] + 1e-6f);
            }
        }
    }
    __syncthreads();

    // ---- DCT + scale + lifter, fp32: 208 threads = 16 frames x 13 ceps ----
    if (tid < 16 * NCEP) {
        const int fl = tid / NCEP, c = tid - fl * NCEP;
        float acc = 0.0f;
        #pragma unroll
        for (int m = 0; m < NMEL; ++m)
            acc += (float)lm[fl * NMEL + m] * ws[WS_DT + m * 13 + c];
        out[(size_t)(blockIdx.x * 16 + fl) * (3 * NCEP) + c] = acc;
    }
}

// ---------------------------------------------------------------------------
// Stage 2: per-batch deltas.
// ---------------------------------------------------------------------------
__global__ __launch_bounds__(128) void mfcc_stage2(float* __restrict__ out)
{
    __shared__ float x [NFRAME * NCEP];
    __shared__ float d1[NFRAME * NCEP];

    const int b = blockIdx.x;
    const int tid = threadIdx.x;
    const int TC = NFRAME * NCEP;

    for (int i = tid; i < TC; i += 128) {
        const int t = i / NCEP, c = i - t * NCEP;
        x[i] = out[((size_t)b * NFRAME + t) * (3 * NCEP) + c];
    }
    __syncthreads();

    for (int i = tid; i < TC; i += 128) {
        const int t = i / NCEP, c = i - t * NCEP;
        float acc = 0.0f;
        #pragma unroll
        for (int k = -2; k <= 2; ++k) {
            if (k == 0) continue;
            int tt = t + k;
            tt = tt < 0 ? 0 : (tt > NFRAME - 1 ? NFRAME - 1 : tt);
            acc += (float)k * x[tt * NCEP + c];
        }
        d1[i] = acc * 0.1f;
    }
    __syncthreads();

    for (int i = tid; i < TC; i += 128) {
        const int t = i / NCEP, c = i - t * NCEP;
        float acc = 0.0f;
        #pragma unroll
        for (int k = -2; k <= 2; ++k) {
            if (k == 0) continue;
            int tt = t + k;
            tt = tt < 0 ? 0 : (tt > NFRAME - 1 ? NFRAME - 1 : tt);
            acc += (float)k * d1[tt * NCEP + c];
        }
        const size_t base = ((size_t)b * NFRAME + t) * (3 * NCEP);
        out[base +     NCEP + c] = d1[i];
        out[base + 2 * NCEP + c] = acc * 0.1f;
    }
}

extern "C" void kernel_launch(void* const* d_in, const int* in_sizes, int n_in,
                              void* d_out, int out_size, void* d_ws, size_t ws_size,
                              hipStream_t stream)
{
    const float* wave   = (const float*)d_in[0];   // [1024][16000] f32
    const float* mel_fb = (const float*)d_in[1];   // [513][40] f32
    float* out = (float*)d_out;                    // [1024][49][39][1] f32
    float* ws  = (float*)d_ws;

    mfcc_prep<<<64, 256, 0, stream>>>(mel_fb, ws);
    mfcc_stage1<<<(BATCH * NFRAME) / 16, 256, 0, stream>>>(wave, ws, out);
    mfcc_stage2<<<BATCH, 128, 0, stream>>>(out);
}

// Round 3
// 163.159 us; speedup vs baseline: 1.6529x; 1.0320x over previous
//
#include <hip/hip_runtime.h>
#include <math.h>

#define NMEL   40
#define NCEP   13
#define BATCH  1024
#define NSAMP  16000
#define NFRAME 49
#define PI_F   3.14159265358979323846f

// d_ws float layout
#define WS_WIN  0        // 640 floats: Hann window
#define WS_R    640      // 512 float2: W_1024^k, k=0..511 (1024 floats)
#define WS_DT   1664     // 520 floats: DCT * 1/sqrt(80) * lifter, [40][13]
#define WS_BT   2184     // f16 area: Bt[48][544] mel weights transposed (13056 floats)
#define WS_TOT  15240

typedef _Float16 half8 __attribute__((ext_vector_type(8)));
typedef __fp16   fp16x2 __attribute__((ext_vector_type(2)));
typedef float f32x4 __attribute__((ext_vector_type(4)));

// DS-only scheduling fence (no instruction emitted, VMEM/VALU permeable).
// mask 0x77 = ALU|VALU|SALU|VMEM may cross; DS bits unset -> ds_* stay ordered.
#define FFT_SB() __builtin_amdgcn_sched_barrier(0x77)

// radix-2 DIF butterfly on register arrays zr/zi (visible via reference alias)
#define BFLY(i0, i1, wr, wi) {                        \
    float tr = zr[i0] - zr[i1], ti = zi[i0] - zi[i1]; \
    zr[i0] += zr[i1]; zi[i0] += zi[i1];               \
    zr[i1] = tr*(wr) - ti*(wi);                       \
    zi[i1] = tr*(wi) + ti*(wr); }

__device__ __forceinline__ unsigned pk_f16(float a, float b) {
    fp16x2 h = __builtin_amdgcn_cvt_pkrtz(a, b);
    union { fp16x2 h; unsigned u; } cvt; cvt.h = h;
    return cvt.u;
}

// ---------------------------------------------------------------------------
// Prep: window / twiddle / DCT tables + transposed, padded f16 mel weights.
// ---------------------------------------------------------------------------
__global__ __launch_bounds__(256) void mfcc_prep(
    const float* __restrict__ mel_fb, float* __restrict__ ws)
{
    const int idx = blockIdx.x * 256 + threadIdx.x;   // grid = 64 blocks

    _Float16* bt = (_Float16*)(ws + WS_BT);
    for (int i = idx; i < 48 * 544; i += 64 * 256) {
        int n = i / 544, k = i - n * 544;
        float v = (n < NMEL && k < 513) ? mel_fb[k * NMEL + n] : 0.0f;
        bt[i] = (_Float16)v;
    }

    if (idx < 640 + 512 + 520) {
        int i = idx;
        if (i < 640) {
            ws[WS_WIN + i] = 0.5f - 0.5f * cosf(2.0f * PI_F * (float)i / 640.0f);
        } else if (i < 1152) {
            int k = i - 640;
            float s, c;
            sincosf(-2.0f * PI_F * (float)k / 1024.0f, &s, &c);
            ((float2*)(ws + WS_R))[k] = make_float2(c, s);
        } else {
            int j = i - 1152;
            int m = j / 13, c0 = j - m * 13;
            float d    = 2.0f * cosf(PI_F * (2.0f * m + 1.0f) * (float)c0 / 80.0f);
            float lift = 1.0f + 11.0f * sinf(PI_F * (float)c0 / 22.0f);
            ws[WS_DT + j] = d * 0.11180339887498949f * lift;   // 1/sqrt(80)
        }
    }
}

// ---------------------------------------------------------------------------
// Stage-1 helper phases (all fully inlined; arrays statically indexed).
// ---------------------------------------------------------------------------
__device__ __forceinline__ void ldFrame(float2 (&x)[5], const float* __restrict__ wave,
                                        int frame, int L)
{
    const int b = frame / NFRAME;
    const int f = frame - b * NFRAME;
    const float2* xp = (const float2*)(wave + (size_t)b * NSAMP + (size_t)f * 320);
    #pragma unroll
    for (int j = 0; j < 5; ++j) x[j] = xp[L + 64 * j];
}

__device__ __forceinline__ void phaseI(float (&zr)[8], float (&zi)[8],
    const float2 (&xv)[5], const float2 (&winv)[5],
    const float2 (&twA)[4], const float2 (&twB)[2], const float2 twC)
{
    #pragma unroll
    for (int j = 0; j < 8; ++j) { zr[j] = 0.0f; zi[j] = 0.0f; }
    #pragma unroll
    for (int j = 0; j < 5; ++j) { zr[j] = xv[j].x * winv[j].x; zi[j] = xv[j].y * winv[j].y; }
    #pragma unroll
    for (int j = 0; j < 4; ++j) BFLY(j, j + 4, twA[j].x, twA[j].y);     // 512
    #pragma unroll
    for (int g = 0; g < 8; g += 4) {                                    // 256
        #pragma unroll
        for (int j = 0; j < 2; ++j) BFLY(g + j, g + j + 2, twB[j].x, twB[j].y);
    }
    #pragma unroll
    for (int i0 = 0; i0 < 8; i0 += 2) BFLY(i0, i0 + 1, twC.x, twC.y);   // 128
}

__device__ __forceinline__ void phaseII(float (&zr)[8], float (&zi)[8],
    const float4 (&q)[4],
    const float2 (&twD)[4], const float2 (&twE)[2], const float2 twF)
{
    zr[0] = q[0].x; zi[0] = q[0].y; zr[1] = q[0].z; zi[1] = q[0].w;
    zr[2] = q[1].x; zi[2] = q[1].y; zr[3] = q[1].z; zi[3] = q[1].w;
    zr[4] = q[2].x; zi[4] = q[2].y; zr[5] = q[2].z; zi[5] = q[2].w;
    zr[6] = q[3].x; zi[6] = q[3].y; zr[7] = q[3].z; zi[7] = q[3].w;
    #pragma unroll
    for (int j = 0; j < 4; ++j) BFLY(j, j + 4, twD[j].x, twD[j].y);     // 64
    #pragma unroll
    for (int g = 0; g < 8; g += 4) {                                    // 32
        #pragma unroll
        for (int j = 0; j < 2; ++j) BFLY(g + j, g + j + 2, twE[j].x, twE[j].y);
    }
    #pragma unroll
    for (int i0 = 0; i0 < 8; i0 += 2) BFLY(i0, i0 + 1, twF.x, twF.y);   // 16
}

__device__ __forceinline__ void phaseIII(float (&zr)[8], float (&zi)[8],
    const float4 (&q)[4])
{
    zr[0] = q[0].x; zi[0] = q[0].y; zr[1] = q[0].z; zi[1] = q[0].w;
    zr[2] = q[1].x; zi[2] = q[1].y; zr[3] = q[1].z; zi[3] = q[1].w;
    zr[4] = q[2].x; zi[4] = q[2].y; zr[5] = q[2].z; zi[5] = q[2].w;
    zr[6] = q[3].x; zi[6] = q[3].y; zr[7] = q[3].z; zi[7] = q[3].w;
    const float C = 0.70710678118654752f;
    const float w8r[4] = { 1.0f,  C, 0.0f, -C };
    const float w8i[4] = { 0.0f, -C, -1.0f, -C };
    #pragma unroll
    for (int j = 0; j < 4; ++j) BFLY(j, j + 4, w8r[j], w8i[j]);         // 8
    #pragma unroll
    for (int g = 0; g < 8; g += 4) {                                    // 4
        BFLY(g + 0, g + 2, 1.0f, 0.0f);
        BFLY(g + 1, g + 3, 0.0f, -1.0f);
    }
    #pragma unroll
    for (int i0 = 0; i0 < 8; i0 += 2) BFLY(i0, i0 + 1, 1.0f, 0.0f);     // 2
}

__device__ __forceinline__ void wrEx1(float2* Z, const float (&zr)[8], const float (&zi)[8],
                                      int s, int a)
{
    #pragma unroll
    for (int j = 0; j < 8; ++j) Z[80 * j + 10 * s + a] = make_float2(zr[j], zi[j]);
}

__device__ __forceinline__ void wrEx2(float2* Z, const float (&zr)[8], const float (&zi)[8],
                                      int s, int a)
{
    #pragma unroll
    for (int j = 0; j < 8; ++j) Z[80 * a + 10 * j + s] = make_float2(zr[j], zi[j]);
}

__device__ __forceinline__ void wrEx3(float2* Z, const float (&zr)[8], const float (&zi)[8],
                                      int u)
{
    const int rev3t[8] = { 0, 4, 2, 6, 1, 5, 3, 7 };
    #pragma unroll
    for (int j = 0; j < 8; ++j) Z[80 * rev3t[j] + u] = make_float2(zr[j], zi[j]);
}

__device__ __forceinline__ void rdEx(const float2* Z, int L, float4 (&q)[4])
{
    q[0] = *(const float4*)&Z[10 * L + 0];
    q[1] = *(const float4*)&Z[10 * L + 2];
    q[2] = *(const float4*)&Z[10 * L + 4];
    q[3] = *(const float4*)&Z[10 * L + 6];
}

__device__ __forceinline__ void rdMag(const float2* Z, int L,
    float4 (&aq)[4], float4 (&tq)[4], float2& b0)
{
    aq[0] = *(const float4*)&Z[10 * L + 0];
    aq[1] = *(const float4*)&Z[10 * L + 2];
    aq[2] = *(const float4*)&Z[10 * L + 4];
    aq[3] = *(const float4*)&Z[10 * L + 6];
    tq[0] = *(const float4*)&Z[630 - 10 * L + 0];   // i=0,1 (j=8,7)
    tq[1] = *(const float4*)&Z[630 - 10 * L + 2];   // i=2,3 (j=6,5)
    tq[2] = *(const float4*)&Z[630 - 10 * L + 4];   // i=4,5 (j=4,3)
    tq[3] = *(const float4*)&Z[630 - 10 * L + 6];   // i=6,7 (j=2,1)
    b0    = Z[640 - 10 * L];                        // j=0 (garbage if L==0)
}

__device__ __forceinline__ void magPhase(const float4 (&aq)[4], const float4 (&tq)[4],
    const float2 b0, const float2 (&twS)[8], const int L, uint4& mgpo, float& m512o)
{
    float Ax[8], Ay[8], Bx[8], By[8];
    Ax[0] = aq[0].x; Ay[0] = aq[0].y; Ax[1] = aq[0].z; Ay[1] = aq[0].w;
    Ax[2] = aq[1].x; Ay[2] = aq[1].y; Ax[3] = aq[1].z; Ay[3] = aq[1].w;
    Ax[4] = aq[2].x; Ay[4] = aq[2].y; Ax[5] = aq[2].z; Ay[5] = aq[2].w;
    Ax[6] = aq[3].x; Ay[6] = aq[3].y; Ax[7] = aq[3].z; Ay[7] = aq[3].w;
    Bx[0] = b0.x;    By[0] = b0.y;
    Bx[7] = tq[0].z; By[7] = tq[0].w;
    Bx[6] = tq[1].x; By[6] = tq[1].y;
    Bx[5] = tq[1].z; By[5] = tq[1].w;
    Bx[4] = tq[2].x; By[4] = tq[2].y;
    Bx[3] = tq[2].z; By[3] = tq[2].w;
    Bx[2] = tq[3].x; By[2] = tq[3].y;
    Bx[1] = tq[3].z; By[1] = tq[3].w;
    float mg[8];
    #pragma unroll
    for (int j = 0; j < 8; ++j) {
        int k = 8 * L + j;
        if (k == 0) {                    // lane 0, j 0 only
            mg[j]  = fabsf(Ax[0] + Ay[0]);
            m512o  = fabsf(Ax[0] - Ay[0]);
        } else {
            float xer = 0.5f * (Ax[j] + Bx[j]), xei = 0.5f * (Ay[j] - By[j]);
            float xo  = 0.5f * (Ay[j] + By[j]), xoi = -0.5f * (Ax[j] - Bx[j]);
            float xr = xer + twS[j].x * xo - twS[j].y * xoi;
            float xi = xei + twS[j].x * xoi + twS[j].y * xo;
            mg[j] = sqrtf(xr * xr + xi * xi);
        }
    }
    mgpo.x = pk_f16(mg[0], mg[1]);
    mgpo.y = pk_f16(mg[2], mg[3]);
    mgpo.z = pk_f16(mg[4], mg[5]);
    mgpo.w = pk_f16(mg[6], mg[7]);
}

// ---------------------------------------------------------------------------
// Stage 1: 16 frames per block (4 waves x 2 PAIRS of pipelined FFTs).
// r10: all LDS phases use slot(x) = x + 2*(x>>3) padding; writes <=2-way-
// conflict-free, reads lane-contiguous 16B-aligned ds_read_b128.
// r11/r12: DS-only sched_barrier fences + sample prefetch, plain bounds.
// r13: 2-frame software pipeline within each wave, SINGLE Z buffer. A wave's
// DS ops execute in order, so interleaving wr1A rd1A wr1B rd1B wr2A ... is
// race-free, and each read's latency is covered by the OTHER frame's
// butterfly/mag VALU phase (~200 cy) instead of stalling the wave. This was
// the wall: r12's counters showed wall = VALU + DS summed (no overlap at
// 1.5 waves/SIMD). Also: lm moved into dead space above the mag tile ->
// LDS 21760 -> 20496 B/block (one more resident block on any pool size).
// ---------------------------------------------------------------------------
__global__ __launch_bounds__(256) void mfcc_stage1(
    const float* __restrict__ wave, const float* __restrict__ ws,
    float* __restrict__ out)
{
    // LDS: float2 Z[4][640] (20480 B) overlaid by f16 mag[16][552] (17664 B);
    // lm[16][40] f16 (1280 B) lives at +17664 (dead space above mag tile).
    // +16 B guard: lane0's don't-care Z[640-0] read from wave 3.
    __shared__ __align__(16) char smem[4 * 640 * 8 + 16];
    char* smemc = smem;
    _Float16* lm = (_Float16*)(smem + 16 * 1104);    // [16][40] f16 @ 17664

    const int tid = threadIdx.x;
    const int wv  = tid >> 6;
    const int L   = tid & 63;
    const int s   = L & 7;
    const int a   = L >> 3;

    float2* Z = (float2*)smem + wv * 640;            // wave-private FFT buffer
    const float2* R   = (const float2*)(ws + WS_R);
    const float2* win = (const float2*)(ws + WS_WIN);

    // ---- hoist all loop-invariant tables into registers (once per wave) ----
    float2 twA[4], twB[2], twC, twD[4], twE[2], twF, twS[8], winv[5];
    #pragma unroll
    for (int j = 0; j < 4; ++j) twA[j] = R[2 * (L + 64 * j)];
    #pragma unroll
    for (int j = 0; j < 2; ++j) twB[j] = R[4 * (L + 64 * j)];
    twC = R[8 * L];
    #pragma unroll
    for (int j = 0; j < 4; ++j) twD[j] = R[128 * j + 16 * s];
    #pragma unroll
    for (int j = 0; j < 2; ++j) twE[j] = R[256 * j + 32 * s];
    twF = R[64 * s];
    #pragma unroll
    for (int j = 0; j < 8; ++j) twS[j] = R[8 * L + j];   // real-split W_1024^k
    #pragma unroll
    for (int j = 0; j < 5; ++j) winv[j] = win[L + 64 * j];

    // bit-reverse slot base for the final write, loop-invariant
    const int r6 = (int)(__brev((unsigned)L) >> 26);
    const int u  = r6 + 2 * (r6 >> 3);

    uint4 mgp[4];          // per-frame packed f16 magnitudes (8 per lane)
    float m512v[4] = {0.0f, 0.0f, 0.0f, 0.0f};

    const int fbase = blockIdx.x * 16 + wv * 4;

    // prefetch pair 0's samples
    float2 xA[5], xB[5];
    ldFrame(xA, wave, fbase + 0, L);
    ldFrame(xB, wave, fbase + 1, L);

    #pragma unroll
    for (int p = 0; p < 2; ++p) {
        // prefetch next pair during this pair's compute (VMEM, fence-permeable)
        float2 xA2[5], xB2[5];
        if (p == 0) {
            ldFrame(xA2, wave, fbase + 2, L);
            ldFrame(xB2, wave, fbase + 3, L);
        }

        float zrA[8], ziA[8], zrB[8], ziB[8];
        float4 qA[4], qB[4];

        // ---- exchange-1 round ----
        phaseI(zrA, ziA, xA, winv, twA, twB, twC);
        FFT_SB();
        wrEx1(Z, zrA, ziA, s, a);
        FFT_SB();
        rdEx(Z, L, qA);                 // rd1A: latency covered by phaseI(B)
        FFT_SB();
        phaseI(zrB, ziB, xB, winv, twA, twB, twC);
        wrEx1(Z, zrB, ziB, s, a);       // DS order: after rd1A ✓
        FFT_SB();
        rdEx(Z, L, qB);                 // rd1B: covered by phaseII(A)
        FFT_SB();

        // ---- exchange-2 round ----
        phaseII(zrA, ziA, qA, twD, twE, twF);
        wrEx2(Z, zrA, ziA, s, a);       // after rd1B ✓
        FFT_SB();
        rdEx(Z, L, qA);                 // rd2A: covered by phaseII(B)
        FFT_SB();
        phaseII(zrB, ziB, qB, twD, twE, twF);
        wrEx2(Z, zrB, ziB, s, a);       // after rd2A ✓
        FFT_SB();
        rdEx(Z, L, qB);                 // rd2B: covered by phaseIII(A)
        FFT_SB();

        // ---- final bit-reverse round + real-split reads ----
        phaseIII(zrA, ziA, qA);
        wrEx3(Z, zrA, ziA, u);          // after rd2B ✓
        FFT_SB();
        float4 aqA[4], tqA[4]; float2 b0A;
        rdMag(Z, L, aqA, tqA, b0A);     // rd3A: covered by phaseIII(B)
        FFT_SB();
        phaseIII(zrB, ziB, qB);
        wrEx3(Z, zrB, ziB, u);          // after rd3A ✓
        FFT_SB();
        float4 aqB[4], tqB[4]; float2 b0B;
        rdMag(Z, L, aqB, tqB, b0B);     // rd3B: covered by magPhase(A)
        FFT_SB();

        // ---- magnitudes ----
        magPhase(aqA, tqA, b0A, twS, L, mgp[2 * p + 0], m512v[2 * p + 0]);
        magPhase(aqB, tqB, b0B, twS, L, mgp[2 * p + 1], m512v[2 * p + 1]);
        FFT_SB();   // Z reads ordered before next pair's writes

        if (p == 0) {
            #pragma unroll
            for (int j = 0; j < 5; ++j) { xA[j] = xA2[j]; xB[j] = xB2[j]; }
        }
    }

    // ---- all FFTs done: overlay mag tile [16][552] f16 onto smem ----
    __syncthreads();
    #pragma unroll
    for (int fi = 0; fi < 4; ++fi) {
        const int row = wv * 4 + fi;
        *(uint4*)(smemc + row * 1104 + 16 * L) = mgp[fi];
        if (L < 20) {   // zero pad bins [512..552), bin 512 = m512
            unsigned v = (L == 0) ? pk_f16(m512v[fi], 0.0f) : 0u;
            *(unsigned*)(smemc + row * 1104 + 1024 + 4 * L) = v;
        }
    }
    __syncthreads();

    // ---- mel projection: D[16 frames][16 mels] per wave, K = 544 ----
    if (wv < 3) {
        const int nl = L & 15, q = L >> 4;
        const char* ap = smemc + nl * 1104 + q * 16;                // A: frame rows
        const _Float16* btp = (const _Float16*)(ws + WS_BT)
                              + (size_t)(wv * 16 + nl) * 544 + q * 8;
        f32x4 acc = {0.0f, 0.0f, 0.0f, 0.0f};
        #pragma unroll
        for (int kk = 0; kk < 17; ++kk) {
            half8 av = *(const half8*)(ap + kk * 64);
            half8 bv = *(const half8*)(btp + kk * 32);
            acc = __builtin_amdgcn_mfma_f32_16x16x32_f16(av, bv, acc, 0, 0, 0);
        }
        const int mel = wv * 16 + nl;
        if (mel < NMEL) {
            #pragma unroll
            for (int r = 0; r < 4; ++r) {
                int fl = q * 4 + r;                 // C/D: row=(lane>>4)*4+r
                lm[fl * NMEL + mel] = (_Float16)__logf(acc[r] + 1e-6f);
            }
        }
    }
    __syncthreads();

    // ---- DCT + scale + lifter, fp32: 208 threads = 16 frames x 13 ceps ----
    if (tid < 16 * NCEP) {
        const int fl = tid / NCEP, c = tid - fl * NCEP;
        float acc = 0.0f;
        #pragma unroll
        for (int m = 0; m < NMEL; ++m)
            acc += (float)lm[fl * NMEL + m] * ws[WS_DT + m * 13 + c];
        out[(size_t)(blockIdx.x * 16 + fl) * (3 * NCEP) + c] = acc;
    }
}

// ---------------------------------------------------------------------------
// Stage 2: per-batch deltas.
// ---------------------------------------------------------------------------
__global__ __launch_bounds__(128) void mfcc_stage2(float* __restrict__ out)
{
    __shared__ float x [NFRAME * NCEP];
    __shared__ float d1[NFRAME * NCEP];

    const int b = blockIdx.x;
    const int tid = threadIdx.x;
    const int TC = NFRAME * NCEP;

    for (int i = tid; i < TC; i += 128) {
        const int t = i / NCEP, c = i - t * NCEP;
        x[i] = out[((size_t)b * NFRAME + t) * (3 * NCEP) + c];
    }
    __syncthreads();

    for (int i = tid; i < TC; i += 128) {
        const int t = i / NCEP, c = i - t * NCEP;
        float acc = 0.0f;
        #pragma unroll
        for (int k = -2; k <= 2; ++k) {
            if (k == 0) continue;
            int tt = t + k;
            tt = tt < 0 ? 0 : (tt > NFRAME - 1 ? NFRAME - 1 : tt);
            acc += (float)k * x[tt * NCEP + c];
        }
        d1[i] = acc * 0.1f;
    }
    __syncthreads();

    for (int i = tid; i < TC; i += 128) {
        const int t = i / NCEP, c = i - t * NCEP;
        float acc = 0.0f;
        #pragma unroll
        for (int k = -2; k <= 2; ++k) {
            if (k == 0) continue;
            int tt = t + k;
            tt = tt < 0 ? 0 : (tt > NFRAME - 1 ? NFRAME - 1 : tt);
            acc += (float)k * d1[tt * NCEP + c];
        }
        const size_t base = ((size_t)b * NFRAME + t) * (3 * NCEP);
        out[base +     NCEP + c] = d1[i];
        out[base + 2 * NCEP + c] = acc * 0.1f;
    }
}

extern "C" void kernel_launch(void* const* d_in, const int* in_sizes, int n_in,
                              void* d_out, int out_size, void* d_ws, size_t ws_size,
                              hipStream_t stream)
{
    const float* wave   = (const float*)d_in[0];   // [1024][16000] f32
    const float* mel_fb = (const float*)d_in[1];   // [513][40] f32
    float* out = (float*)d_out;                    // [1024][49][39][1] f32
    float* ws  = (float*)d_ws;

    mfcc_prep<<<64, 256, 0, stream>>>(mel_fb, ws);
    mfcc_stage1<<<(BATCH * NFRAME) / 16, 256, 0, stream>>>(wave, ws, out);
    mfcc_stage2<<<BATCH, 128, 0, stream>>>(out);
}

// Round 4
// 151.966 us; speedup vs baseline: 1.7746x; 1.0737x over previous
//
#include <hip/hip_runtime.h>
#include <math.h>

#define NMEL   40
#define NCEP   13
#define BATCH  1024
#define NSAMP  16000
#define NFRAME 49
#define PI_F   3.14159265358979323846f

// d_ws float layout
#define WS_WIN  0        // 640 floats: Hann window
#define WS_R    640      // 512 float2: W_1024^k, k=0..511 (1024 floats)
#define WS_DT   1664     // 520 floats: DCT * 1/sqrt(80) * lifter, [40][13]
#define WS_BT   2184     // f16 area: Bt[48][544] mel weights transposed (13056 floats)
#define WS_TOT  15240

typedef _Float16 half8 __attribute__((ext_vector_type(8)));
typedef __fp16   fp16x2 __attribute__((ext_vector_type(2)));
typedef float f32x4 __attribute__((ext_vector_type(4)));

// DS-only scheduling fence (no instruction emitted, VMEM/VALU permeable).
// mask 0x77 = ALU|VALU|SALU|VMEM may cross; DS bits unset -> ds_* stay ordered.
#define FFT_SB() __builtin_amdgcn_sched_barrier(0x77)

// radix-2 DIF butterfly on register arrays zr/zi (visible via reference alias)
#define BFLY(i0, i1, wr, wi) {                        \
    float tr = zr[i0] - zr[i1], ti = zi[i0] - zi[i1]; \
    zr[i0] += zr[i1]; zi[i0] += zi[i1];               \
    zr[i1] = tr*(wr) - ti*(wi);                       \
    zi[i1] = tr*(wi) + ti*(wr); }

__device__ __forceinline__ unsigned pk_f16(float a, float b) {
    fp16x2 h = __builtin_amdgcn_cvt_pkrtz(a, b);
    union { fp16x2 h; unsigned u; } cvt; cvt.h = h;
    return cvt.u;
}

// ---------------------------------------------------------------------------
// Prep: window / twiddle / DCT tables + transposed, padded f16 mel weights.
// ---------------------------------------------------------------------------
__global__ __launch_bounds__(256) void mfcc_prep(
    const float* __restrict__ mel_fb, float* __restrict__ ws)
{
    const int idx = blockIdx.x * 256 + threadIdx.x;   // grid = 64 blocks

    _Float16* bt = (_Float16*)(ws + WS_BT);
    for (int i = idx; i < 48 * 544; i += 64 * 256) {
        int n = i / 544, k = i - n * 544;
        float v = (n < NMEL && k < 513) ? mel_fb[k * NMEL + n] : 0.0f;
        bt[i] = (_Float16)v;
    }

    if (idx < 640 + 512 + 520) {
        int i = idx;
        if (i < 640) {
            ws[WS_WIN + i] = 0.5f - 0.5f * cosf(2.0f * PI_F * (float)i / 640.0f);
        } else if (i < 1152) {
            int k = i - 640;
            float s, c;
            sincosf(-2.0f * PI_F * (float)k / 1024.0f, &s, &c);
            ((float2*)(ws + WS_R))[k] = make_float2(c, s);
        } else {
            int j = i - 1152;
            int m = j / 13, c0 = j - m * 13;
            float d    = 2.0f * cosf(PI_F * (2.0f * m + 1.0f) * (float)c0 / 80.0f);
            float lift = 1.0f + 11.0f * sinf(PI_F * (float)c0 / 22.0f);
            ws[WS_DT + j] = d * 0.11180339887498949f * lift;   // 1/sqrt(80)
        }
    }
}

// ---------------------------------------------------------------------------
// Stage-1 helper phases (all fully inlined; arrays statically indexed).
// ---------------------------------------------------------------------------
__device__ __forceinline__ void ldFrame(float2 (&x)[5], const float* __restrict__ wave,
                                        int frame, int L)
{
    const int b = frame / NFRAME;
    const int f = frame - b * NFRAME;
    const float2* xp = (const float2*)(wave + (size_t)b * NSAMP + (size_t)f * 320);
    #pragma unroll
    for (int j = 0; j < 5; ++j) x[j] = xp[L + 64 * j];
}

__device__ __forceinline__ void phaseI(float (&zr)[8], float (&zi)[8],
    const float2 (&xv)[5], const float2 (&winv)[5],
    const float2 (&twA)[4], const float2 (&twB)[2], const float2 twC)
{
    #pragma unroll
    for (int j = 0; j < 8; ++j) { zr[j] = 0.0f; zi[j] = 0.0f; }
    #pragma unroll
    for (int j = 0; j < 5; ++j) { zr[j] = xv[j].x * winv[j].x; zi[j] = xv[j].y * winv[j].y; }
    #pragma unroll
    for (int j = 0; j < 4; ++j) BFLY(j, j + 4, twA[j].x, twA[j].y);     // 512
    #pragma unroll
    for (int g = 0; g < 8; g += 4) {                                    // 256
        #pragma unroll
        for (int j = 0; j < 2; ++j) BFLY(g + j, g + j + 2, twB[j].x, twB[j].y);
    }
    #pragma unroll
    for (int i0 = 0; i0 < 8; i0 += 2) BFLY(i0, i0 + 1, twC.x, twC.y);   // 128
}

__device__ __forceinline__ void phaseII(float (&zr)[8], float (&zi)[8],
    const float4 (&q)[4],
    const float2 (&twD)[4], const float2 (&twE)[2], const float2 twF)
{
    zr[0] = q[0].x; zi[0] = q[0].y; zr[1] = q[0].z; zi[1] = q[0].w;
    zr[2] = q[1].x; zi[2] = q[1].y; zr[3] = q[1].z; zi[3] = q[1].w;
    zr[4] = q[2].x; zi[4] = q[2].y; zr[5] = q[2].z; zi[5] = q[2].w;
    zr[6] = q[3].x; zi[6] = q[3].y; zr[7] = q[3].z; zi[7] = q[3].w;
    #pragma unroll
    for (int j = 0; j < 4; ++j) BFLY(j, j + 4, twD[j].x, twD[j].y);     // 64
    #pragma unroll
    for (int g = 0; g < 8; g += 4) {                                    // 32
        #pragma unroll
        for (int j = 0; j < 2; ++j) BFLY(g + j, g + j + 2, twE[j].x, twE[j].y);
    }
    #pragma unroll
    for (int i0 = 0; i0 < 8; i0 += 2) BFLY(i0, i0 + 1, twF.x, twF.y);   // 16
}

__device__ __forceinline__ void phaseIII(float (&zr)[8], float (&zi)[8],
    const float4 (&q)[4])
{
    zr[0] = q[0].x; zi[0] = q[0].y; zr[1] = q[0].z; zi[1] = q[0].w;
    zr[2] = q[1].x; zi[2] = q[1].y; zr[3] = q[1].z; zi[3] = q[1].w;
    zr[4] = q[2].x; zi[4] = q[2].y; zr[5] = q[2].z; zi[5] = q[2].w;
    zr[6] = q[3].x; zi[6] = q[3].y; zr[7] = q[3].z; zi[7] = q[3].w;
    const float C = 0.70710678118654752f;
    const float w8r[4] = { 1.0f,  C, 0.0f, -C };
    const float w8i[4] = { 0.0f, -C, -1.0f, -C };
    #pragma unroll
    for (int j = 0; j < 4; ++j) BFLY(j, j + 4, w8r[j], w8i[j]);         // 8
    #pragma unroll
    for (int g = 0; g < 8; g += 4) {                                    // 4
        BFLY(g + 0, g + 2, 1.0f, 0.0f);
        BFLY(g + 1, g + 3, 0.0f, -1.0f);
    }
    #pragma unroll
    for (int i0 = 0; i0 < 8; i0 += 2) BFLY(i0, i0 + 1, 1.0f, 0.0f);     // 2
}

__device__ __forceinline__ void wrEx1(float2* Z, const float (&zr)[8], const float (&zi)[8],
                                      int s, int a)
{
    #pragma unroll
    for (int j = 0; j < 8; ++j) Z[80 * j + 10 * s + a] = make_float2(zr[j], zi[j]);
}

__device__ __forceinline__ void wrEx2(float2* Z, const float (&zr)[8], const float (&zi)[8],
                                      int s, int a)
{
    #pragma unroll
    for (int j = 0; j < 8; ++j) Z[80 * a + 10 * j + s] = make_float2(zr[j], zi[j]);
}

__device__ __forceinline__ void wrEx3(float2* Z, const float (&zr)[8], const float (&zi)[8],
                                      int u)
{
    const int rev3t[8] = { 0, 4, 2, 6, 1, 5, 3, 7 };
    #pragma unroll
    for (int j = 0; j < 8; ++j) Z[80 * rev3t[j] + u] = make_float2(zr[j], zi[j]);
}

__device__ __forceinline__ void rdEx(const float2* Z, int L, float4 (&q)[4])
{
    q[0] = *(const float4*)&Z[10 * L + 0];
    q[1] = *(const float4*)&Z[10 * L + 2];
    q[2] = *(const float4*)&Z[10 * L + 4];
    q[3] = *(const float4*)&Z[10 * L + 6];
}

__device__ __forceinline__ void rdMag(const float2* Z, int L,
    float4 (&aq)[4], float4 (&tq)[4], float2& b0)
{
    aq[0] = *(const float4*)&Z[10 * L + 0];
    aq[1] = *(const float4*)&Z[10 * L + 2];
    aq[2] = *(const float4*)&Z[10 * L + 4];
    aq[3] = *(const float4*)&Z[10 * L + 6];
    tq[0] = *(const float4*)&Z[630 - 10 * L + 0];   // i=0,1 (j=8,7)
    tq[1] = *(const float4*)&Z[630 - 10 * L + 2];   // i=2,3 (j=6,5)
    tq[2] = *(const float4*)&Z[630 - 10 * L + 4];   // i=4,5 (j=4,3)
    tq[3] = *(const float4*)&Z[630 - 10 * L + 6];   // i=6,7 (j=2,1)
    b0    = Z[640 - 10 * L];                        // j=0 (garbage if L==0)
}

// r14: branchless general path for all 8 bins + single lane-0 fixup (the old
// per-j `if (k==0)` kept 8 compares + dual paths live). sqrt via
// __builtin_amdgcn_sqrtf (1x v_sqrt_f32, ~1ulp; absmax budget 0.25 is safe)
// instead of libm's correctly-rounded multi-instruction sequence.
__device__ __forceinline__ void magPhase(const float4 (&aq)[4], const float4 (&tq)[4],
    const float2 b0, const float2 (&twS)[8], const int L, uint4& mgpo, float& m512o)
{
    float Ax[8], Ay[8], Bx[8], By[8];
    Ax[0] = aq[0].x; Ay[0] = aq[0].y; Ax[1] = aq[0].z; Ay[1] = aq[0].w;
    Ax[2] = aq[1].x; Ay[2] = aq[1].y; Ax[3] = aq[1].z; Ay[3] = aq[1].w;
    Ax[4] = aq[2].x; Ay[4] = aq[2].y; Ax[5] = aq[2].z; Ay[5] = aq[2].w;
    Ax[6] = aq[3].x; Ay[6] = aq[3].y; Ax[7] = aq[3].z; Ay[7] = aq[3].w;
    Bx[0] = b0.x;    By[0] = b0.y;
    Bx[7] = tq[0].z; By[7] = tq[0].w;
    Bx[6] = tq[1].x; By[6] = tq[1].y;
    Bx[5] = tq[1].z; By[5] = tq[1].w;
    Bx[4] = tq[2].x; By[4] = tq[2].y;
    Bx[3] = tq[2].z; By[3] = tq[2].w;
    Bx[2] = tq[3].x; By[2] = tq[3].y;
    Bx[1] = tq[3].z; By[1] = tq[3].w;
    float mg[8];
    #pragma unroll
    for (int j = 0; j < 8; ++j) {
        float xer = 0.5f * (Ax[j] + Bx[j]), xei = 0.5f * (Ay[j] - By[j]);
        float xo  = 0.5f * (Ay[j] + By[j]), xoi = -0.5f * (Ax[j] - Bx[j]);
        float xr = xer + twS[j].x * xo - twS[j].y * xoi;
        float xi = xei + twS[j].x * xoi + twS[j].y * xo;
        mg[j] = __builtin_amdgcn_sqrtf(xr * xr + xi * xi);
    }
    if (L == 0) {                        // bin k=0: X[0] = sum, m512 = alt-sum
        mg[0]  = fabsf(Ax[0] + Ay[0]);
        m512o  = fabsf(Ax[0] - Ay[0]);
    }
    mgpo.x = pk_f16(mg[0], mg[1]);
    mgpo.y = pk_f16(mg[2], mg[3]);
    mgpo.z = pk_f16(mg[4], mg[5]);
    mgpo.w = pk_f16(mg[6], mg[7]);
}

// ---------------------------------------------------------------------------
// Stage 1: 16 frames per block (4 waves x 2 PAIRS of pipelined FFTs).
// r10: slot(x) = x + 2*(x>>3) padding; writes <=2-way-conflict-free, reads
// lane-contiguous 16B-aligned ds_read_b128.
// r11/r12: DS-only sched_barrier fences + sample prefetch, plain bounds.
// r13: 2-frame software pipeline per wave, single Z buffer (in-order DS).
// r14: pair loop NOT unrolled (#pragma unroll 1): the fully-unrolled body was
// ~30 KB of straight-line code — I$-streaming was the prime suspect for the
// ~60% no-issue cycles (DS+VMEM latency models can't produce them). Halving
// the body and gaining back-edge I$ reuse tests/fixes that. mgp/m512 rotate
// through NAMED registers at the loop tail (runtime-indexed arrays would go
// to scratch — rule #20).
// ---------------------------------------------------------------------------
__global__ __launch_bounds__(256) void mfcc_stage1(
    const float* __restrict__ wave, const float* __restrict__ ws,
    float* __restrict__ out)
{
    // LDS: float2 Z[4][640] (20480 B) overlaid by f16 mag[16][552] (17664 B);
    // lm[16][40] f16 (1280 B) lives at +17664 (dead space above mag tile).
    // +16 B guard: lane0's don't-care Z[640-0] read from wave 3.
    __shared__ __align__(16) char smem[4 * 640 * 8 + 16];
    char* smemc = smem;
    _Float16* lm = (_Float16*)(smem + 16 * 1104);    // [16][40] f16 @ 17664

    const int tid = threadIdx.x;
    const int wv  = tid >> 6;
    const int L   = tid & 63;
    const int s   = L & 7;
    const int a   = L >> 3;

    float2* Z = (float2*)smem + wv * 640;            // wave-private FFT buffer
    const float2* R   = (const float2*)(ws + WS_R);
    const float2* win = (const float2*)(ws + WS_WIN);

    // ---- hoist all loop-invariant tables into registers (once per wave) ----
    float2 twA[4], twB[2], twC, twD[4], twE[2], twF, twS[8], winv[5];
    #pragma unroll
    for (int j = 0; j < 4; ++j) twA[j] = R[2 * (L + 64 * j)];
    #pragma unroll
    for (int j = 0; j < 2; ++j) twB[j] = R[4 * (L + 64 * j)];
    twC = R[8 * L];
    #pragma unroll
    for (int j = 0; j < 4; ++j) twD[j] = R[128 * j + 16 * s];
    #pragma unroll
    for (int j = 0; j < 2; ++j) twE[j] = R[256 * j + 32 * s];
    twF = R[64 * s];
    #pragma unroll
    for (int j = 0; j < 8; ++j) twS[j] = R[8 * L + j];   // real-split W_1024^k
    #pragma unroll
    for (int j = 0; j < 5; ++j) winv[j] = win[L + 64 * j];

    // bit-reverse slot base for the final write, loop-invariant
    const int r6 = (int)(__brev((unsigned)L) >> 26);
    const int u  = r6 + 2 * (r6 >> 3);

    // per-frame packed f16 magnitudes, rotated through named regs (no dynamic
    // indexing -> no scratch). After 2 iterations: mgp0..3 = frames 0..3.
    uint4 mgp0, mgp1, mgp2, mgp3;
    float m5120 = 0.0f, m5121 = 0.0f, m5122 = 0.0f, m5123 = 0.0f;

    const int fbase = blockIdx.x * 16 + wv * 4;

    // prefetch pair 0's samples
    float2 xA[5], xB[5];
    ldFrame(xA, wave, fbase + 0, L);
    ldFrame(xB, wave, fbase + 1, L);

    #pragma unroll 1
    for (int p = 0; p < 2; ++p) {
        // prefetch next pair during this pair's compute (VMEM, fence-permeable)
        float2 xA2[5], xB2[5];
        if (p == 0) {
            ldFrame(xA2, wave, fbase + 2, L);
            ldFrame(xB2, wave, fbase + 3, L);
        }

        float zrA[8], ziA[8], zrB[8], ziB[8];
        float4 qA[4], qB[4];

        // ---- exchange-1 round ----
        phaseI(zrA, ziA, xA, winv, twA, twB, twC);
        FFT_SB();
        wrEx1(Z, zrA, ziA, s, a);
        FFT_SB();
        rdEx(Z, L, qA);                 // rd1A: latency covered by phaseI(B)
        FFT_SB();
        phaseI(zrB, ziB, xB, winv, twA, twB, twC);
        wrEx1(Z, zrB, ziB, s, a);       // DS order: after rd1A ✓
        FFT_SB();
        rdEx(Z, L, qB);                 // rd1B: covered by phaseII(A)
        FFT_SB();

        // ---- exchange-2 round ----
        phaseII(zrA, ziA, qA, twD, twE, twF);
        wrEx2(Z, zrA, ziA, s, a);       // after rd1B ✓
        FFT_SB();
        rdEx(Z, L, qA);                 // rd2A: covered by phaseII(B)
        FFT_SB();
        phaseII(zrB, ziB, qB, twD, twE, twF);
        wrEx2(Z, zrB, ziB, s, a);       // after rd2A ✓
        FFT_SB();
        rdEx(Z, L, qB);                 // rd2B: covered by phaseIII(A)
        FFT_SB();

        // ---- final bit-reverse round + real-split reads ----
        phaseIII(zrA, ziA, qA);
        wrEx3(Z, zrA, ziA, u);          // after rd2B ✓
        FFT_SB();
        float4 aqA[4], tqA[4]; float2 b0A;
        rdMag(Z, L, aqA, tqA, b0A);     // rd3A: covered by phaseIII(B)
        FFT_SB();
        phaseIII(zrB, ziB, qB);
        wrEx3(Z, zrB, ziB, u);          // after rd3A ✓
        FFT_SB();
        float4 aqB[4], tqB[4]; float2 b0B;
        rdMag(Z, L, aqB, tqB, b0B);     // rd3B: covered by magPhase(A)
        FFT_SB();

        // ---- magnitudes ----
        uint4 mgA, mgB;
        float mA = 0.0f, mB = 0.0f;
        magPhase(aqA, tqA, b0A, twS, L, mgA, mA);
        magPhase(aqB, tqB, b0B, twS, L, mgB, mB);
        FFT_SB();   // Z reads ordered before next pair's writes

        // rotate the result queue (static register moves)
        mgp0 = mgp2;  mgp1 = mgp3;  mgp2 = mgA;  mgp3 = mgB;
        m5120 = m5122; m5121 = m5123; m5122 = mA; m5123 = mB;

        if (p == 0) {
            #pragma unroll
            for (int j = 0; j < 5; ++j) { xA[j] = xA2[j]; xB[j] = xB2[j]; }
        }
    }

    // ---- all FFTs done: overlay mag tile [16][552] f16 onto smem ----
    __syncthreads();
    {
        const int row = wv * 4;
        *(uint4*)(smemc + (row + 0) * 1104 + 16 * L) = mgp0;
        *(uint4*)(smemc + (row + 1) * 1104 + 16 * L) = mgp1;
        *(uint4*)(smemc + (row + 2) * 1104 + 16 * L) = mgp2;
        *(uint4*)(smemc + (row + 3) * 1104 + 16 * L) = mgp3;
        if (L < 20) {   // zero pad bins [512..552), bin 512 = m512
            unsigned v0 = (L == 0) ? pk_f16(m5120, 0.0f) : 0u;
            unsigned v1 = (L == 0) ? pk_f16(m5121, 0.0f) : 0u;
            unsigned v2 = (L == 0) ? pk_f16(m5122, 0.0f) : 0u;
            unsigned v3 = (L == 0) ? pk_f16(m5123, 0.0f) : 0u;
            *(unsigned*)(smemc + (row + 0) * 1104 + 1024 + 4 * L) = v0;
            *(unsigned*)(smemc + (row + 1) * 1104 + 1024 + 4 * L) = v1;
            *(unsigned*)(smemc + (row + 2) * 1104 + 1024 + 4 * L) = v2;
            *(unsigned*)(smemc + (row + 3) * 1104 + 1024 + 4 * L) = v3;
        }
    }
    __syncthreads();

    // ---- mel projection: D[16 frames][16 mels] per wave, K = 544 ----
    if (wv < 3) {
        const int nl = L & 15, q = L >> 4;
        const char* ap = smemc + nl * 1104 + q * 16;                // A: frame rows
        const _Float16* btp = (const _Float16*)(ws + WS_BT)
                              + (size_t)(wv * 16 + nl) * 544 + q * 8;
        f32x4 acc = {0.0f, 0.0f, 0.0f, 0.0f};
        #pragma unroll
        for (int kk = 0; kk < 17; ++kk) {
            half8 av = *(const half8*)(ap + kk * 64);
            half8 bv = *(const half8*)(btp + kk * 32);
            acc = __builtin_amdgcn_mfma_f32_16x16x32_f16(av, bv, acc, 0, 0, 0);
        }
        const int mel = wv * 16 + nl;
        if (mel < NMEL) {
            #pragma unroll
            for (int r = 0; r < 4; ++r) {
                int fl = q * 4 + r;                 // C/D: row=(lane>>4)*4+r
                lm[fl * NMEL + mel] = (_Float16)__logf(acc[r] + 1e-6f);
            }
        }
    }
    __syncthreads();

    // ---- DCT + scale + lifter, fp32: 208 threads = 16 frames x 13 ceps ----
    if (tid < 16 * NCEP) {
        const int fl = tid / NCEP, c = tid - fl * NCEP;
        float acc = 0.0f;
        #pragma unroll
        for (int m = 0; m < NMEL; ++m)
            acc += (float)lm[fl * NMEL + m] * ws[WS_DT + m * 13 + c];
        out[(size_t)(blockIdx.x * 16 + fl) * (3 * NCEP) + c] = acc;
    }
}

// ---------------------------------------------------------------------------
// Stage 2: per-batch deltas.
// ---------------------------------------------------------------------------
__global__ __launch_bounds__(128) void mfcc_stage2(float* __restrict__ out)
{
    __shared__ float x [NFRAME * NCEP];
    __shared__ float d1[NFRAME * NCEP];

    const int b = blockIdx.x;
    const int tid = threadIdx.x;
    const int TC = NFRAME * NCEP;

    for (int i = tid; i < TC; i += 128) {
        const int t = i / NCEP, c = i - t * NCEP;
        x[i] = out[((size_t)b * NFRAME + t) * (3 * NCEP) + c];
    }
    __syncthreads();

    for (int i = tid; i < TC; i += 128) {
        const int t = i / NCEP, c = i - t * NCEP;
        float acc = 0.0f;
        #pragma unroll
        for (int k = -2; k <= 2; ++k) {
            if (k == 0) continue;
            int tt = t + k;
            tt = tt < 0 ? 0 : (tt > NFRAME - 1 ? NFRAME - 1 : tt);
            acc += (float)k * x[tt * NCEP + c];
        }
        d1[i] = acc * 0.1f;
    }
    __syncthreads();

    for (int i = tid; i < TC; i += 128) {
        const int t = i / NCEP, c = i - t * NCEP;
        float acc = 0.0f;
        #pragma unroll
        for (int k = -2; k <= 2; ++k) {
            if (k == 0) continue;
            int tt = t + k;
            tt = tt < 0 ? 0 : (tt > NFRAME - 1 ? NFRAME - 1 : tt);
            acc += (float)k * d1[tt * NCEP + c];
        }
        const size_t base = ((size_t)b * NFRAME + t) * (3 * NCEP);
        out[base +     NCEP + c] = d1[i];
        out[base + 2 * NCEP + c] = acc * 0.1f;
    }
}

extern "C" void kernel_launch(void* const* d_in, const int* in_sizes, int n_in,
                              void* d_out, int out_size, void* d_ws, size_t ws_size,
                              hipStream_t stream)
{
    const float* wave   = (const float*)d_in[0];   // [1024][16000] f32
    const float* mel_fb = (const float*)d_in[1];   // [513][40] f32
    float* out = (float*)d_out;                    // [1024][49][39][1] f32
    float* ws  = (float*)d_ws;

    mfcc_prep<<<64, 256, 0, stream>>>(mel_fb, ws);
    mfcc_stage1<<<(BATCH * NFRAME) / 16, 256, 0, stream>>>(wave, ws, out);
    mfcc_stage2<<<BATCH, 128, 0, stream>>>(out);
}

// Round 5
// 149.678 us; speedup vs baseline: 1.8017x; 1.0153x over previous
//
#include <hip/hip_runtime.h>
#include <math.h>

#define NMEL   40
#define NCEP   13
#define BATCH  1024
#define NSAMP  16000
#define NFRAME 49
#define PI_F   3.14159265358979323846f

// d_ws float layout
#define WS_WIN  0        // 640 floats: Hann window
#define WS_R    640      // 512 float2: W_1024^k, k=0..511 (1024 floats)
#define WS_DT   1664     // 520 floats: DCT * 1/sqrt(80) * lifter, [40][13]
#define WS_BT   2184     // f16 area: Bt[48][544] mel weights transposed (13056 floats)
#define WS_TOT  15240

// exact power-of-2 reciprocals (all exactly representable in f32)
#define INV16    0.0625f
#define INV32    0.03125f
#define INV64    0.015625f
#define INV128   0.0078125f
#define INV256   0.00390625f
#define INV1024  0.0009765625f

typedef _Float16 half8 __attribute__((ext_vector_type(8)));
typedef __fp16   fp16x2 __attribute__((ext_vector_type(2)));
typedef float f32x4 __attribute__((ext_vector_type(4)));

// DS-only scheduling fence (no instruction emitted, VMEM/VALU permeable).
// mask 0x77 = ALU|VALU|SALU|VMEM may cross; DS bits unset -> ds_* stay ordered.
#define FFT_SB() __builtin_amdgcn_sched_barrier(0x77)

// radix-2 DIF butterfly on register arrays zr/zi (visible via reference alias)
#define BFLY(i0, i1, wr, wi) {                        \
    float tr = zr[i0] - zr[i1], ti = zi[i0] - zi[i1]; \
    zr[i0] += zr[i1]; zi[i0] += zi[i1];               \
    zr[i1] = tr*(wr) - ti*(wi);                       \
    zi[i1] = tr*(wi) + ti*(wr); }

__device__ __forceinline__ unsigned pk_f16(float a, float b) {
    fp16x2 h = __builtin_amdgcn_cvt_pkrtz(a, b);
    union { fp16x2 h; unsigned u; } cvt; cvt.h = h;
    return cvt.u;
}

// r15: on-the-fly twiddle. v_sin/v_cos take REVOLUTIONS (D = sin/cos(S0*2pi));
// rev = -k/1024 etc. is an EXACT pow2 division in f32 -> no range reduction,
// error ~1e-6 abs (far below the f16 mag quantization already in the pipe).
// This frees the 36 always-live twiddle table VGPRs (twB/C/D/E/F/S) that were
// capping resident waves.
__device__ __forceinline__ float2 twid(float rev) {
    return make_float2(__builtin_amdgcn_cosf(rev), __builtin_amdgcn_sinf(rev));
}

// ---------------------------------------------------------------------------
// Prep: window / twiddle / DCT tables + transposed, padded f16 mel weights.
// ---------------------------------------------------------------------------
__global__ __launch_bounds__(256) void mfcc_prep(
    const float* __restrict__ mel_fb, float* __restrict__ ws)
{
    const int idx = blockIdx.x * 256 + threadIdx.x;   // grid = 64 blocks

    _Float16* bt = (_Float16*)(ws + WS_BT);
    for (int i = idx; i < 48 * 544; i += 64 * 256) {
        int n = i / 544, k = i - n * 544;
        float v = (n < NMEL && k < 513) ? mel_fb[k * NMEL + n] : 0.0f;
        bt[i] = (_Float16)v;
    }

    if (idx < 640 + 512 + 520) {
        int i = idx;
        if (i < 640) {
            ws[WS_WIN + i] = 0.5f - 0.5f * cosf(2.0f * PI_F * (float)i / 640.0f);
        } else if (i < 1152) {
            int k = i - 640;
            float s, c;
            sincosf(-2.0f * PI_F * (float)k / 1024.0f, &s, &c);
            ((float2*)(ws + WS_R))[k] = make_float2(c, s);
        } else {
            int j = i - 1152;
            int m = j / 13, c0 = j - m * 13;
            float d    = 2.0f * cosf(PI_F * (2.0f * m + 1.0f) * (float)c0 / 80.0f);
            float lift = 1.0f + 11.0f * sinf(PI_F * (float)c0 / 22.0f);
            ws[WS_DT + j] = d * 0.11180339887498949f * lift;   // 1/sqrt(80)
        }
    }
}

// ---------------------------------------------------------------------------
// Stage-1 helper phases (all fully inlined; arrays statically indexed).
// ---------------------------------------------------------------------------
__device__ __forceinline__ void ldFrame(float2 (&x)[5], const float* __restrict__ wave,
                                        int frame, int L)
{
    const int b = frame / NFRAME;
    const int f = frame - b * NFRAME;
    const float2* xp = (const float2*)(wave + (size_t)b * NSAMP + (size_t)f * 320);
    #pragma unroll
    for (int j = 0; j < 5; ++j) x[j] = xp[L + 64 * j];
}

__device__ __forceinline__ void phaseI(float (&zr)[8], float (&zi)[8],
    const float2 (&xv)[5], const float2 (&winv)[5],
    const float2 (&twA)[4], const int L)
{
    // on-the-fly twiddles for the 256/128 stages (rev args exact):
    // twB[j] = W^(4(L+64j)) -> rev = -L/256 - 0.25j ; twC = W^(8L) -> -L/128
    const float bb = -(float)L * INV256;
    float2 twB[2] = { twid(bb), twid(bb - 0.25f) };
    float2 twC    = twid(-(float)L * INV128);

    #pragma unroll
    for (int j = 0; j < 8; ++j) { zr[j] = 0.0f; zi[j] = 0.0f; }
    #pragma unroll
    for (int j = 0; j < 5; ++j) { zr[j] = xv[j].x * winv[j].x; zi[j] = xv[j].y * winv[j].y; }
    #pragma unroll
    for (int j = 0; j < 4; ++j) BFLY(j, j + 4, twA[j].x, twA[j].y);     // 512
    #pragma unroll
    for (int g = 0; g < 8; g += 4) {                                    // 256
        #pragma unroll
        for (int j = 0; j < 2; ++j) BFLY(g + j, g + j + 2, twB[j].x, twB[j].y);
    }
    #pragma unroll
    for (int i0 = 0; i0 < 8; i0 += 2) BFLY(i0, i0 + 1, twC.x, twC.y);   // 128
}

__device__ __forceinline__ void phaseII(float (&zr)[8], float (&zi)[8],
    const float4 (&q)[4], const int s)
{
    // twD[j] = W^(128j+16s) -> rev = -s/64 - 0.125j
    // twE[j] = W^(256j+32s) -> rev = -s/32 - 0.25j ; twF = W^(64s) -> -s/16
    const float d0 = -(float)s * INV64;
    float2 twD[4] = { twid(d0), twid(d0 - 0.125f), twid(d0 - 0.25f), twid(d0 - 0.375f) };
    const float e0 = -(float)s * INV32;
    float2 twE[2] = { twid(e0), twid(e0 - 0.25f) };
    float2 twF    = twid(-(float)s * INV16);

    zr[0] = q[0].x; zi[0] = q[0].y; zr[1] = q[0].z; zi[1] = q[0].w;
    zr[2] = q[1].x; zi[2] = q[1].y; zr[3] = q[1].z; zi[3] = q[1].w;
    zr[4] = q[2].x; zi[4] = q[2].y; zr[5] = q[2].z; zi[5] = q[2].w;
    zr[6] = q[3].x; zi[6] = q[3].y; zr[7] = q[3].z; zi[7] = q[3].w;
    #pragma unroll
    for (int j = 0; j < 4; ++j) BFLY(j, j + 4, twD[j].x, twD[j].y);     // 64
    #pragma unroll
    for (int g = 0; g < 8; g += 4) {                                    // 32
        #pragma unroll
        for (int j = 0; j < 2; ++j) BFLY(g + j, g + j + 2, twE[j].x, twE[j].y);
    }
    #pragma unroll
    for (int i0 = 0; i0 < 8; i0 += 2) BFLY(i0, i0 + 1, twF.x, twF.y);   // 16
}

__device__ __forceinline__ void phaseIII(float (&zr)[8], float (&zi)[8],
    const float4 (&q)[4])
{
    zr[0] = q[0].x; zi[0] = q[0].y; zr[1] = q[0].z; zi[1] = q[0].w;
    zr[2] = q[1].x; zi[2] = q[1].y; zr[3] = q[1].z; zi[3] = q[1].w;
    zr[4] = q[2].x; zi[4] = q[2].y; zr[5] = q[2].z; zi[5] = q[2].w;
    zr[6] = q[3].x; zi[6] = q[3].y; zr[7] = q[3].z; zi[7] = q[3].w;
    const float C = 0.70710678118654752f;
    const float w8r[4] = { 1.0f,  C, 0.0f, -C };
    const float w8i[4] = { 0.0f, -C, -1.0f, -C };
    #pragma unroll
    for (int j = 0; j < 4; ++j) BFLY(j, j + 4, w8r[j], w8i[j]);         // 8
    #pragma unroll
    for (int g = 0; g < 8; g += 4) {                                    // 4
        BFLY(g + 0, g + 2, 1.0f, 0.0f);
        BFLY(g + 1, g + 3, 0.0f, -1.0f);
    }
    #pragma unroll
    for (int i0 = 0; i0 < 8; i0 += 2) BFLY(i0, i0 + 1, 1.0f, 0.0f);     // 2
}

__device__ __forceinline__ void wrEx1(float2* Z, const float (&zr)[8], const float (&zi)[8],
                                      int s, int a)
{
    #pragma unroll
    for (int j = 0; j < 8; ++j) Z[80 * j + 10 * s + a] = make_float2(zr[j], zi[j]);
}

__device__ __forceinline__ void wrEx2(float2* Z, const float (&zr)[8], const float (&zi)[8],
                                      int s, int a)
{
    #pragma unroll
    for (int j = 0; j < 8; ++j) Z[80 * a + 10 * j + s] = make_float2(zr[j], zi[j]);
}

__device__ __forceinline__ void wrEx3(float2* Z, const float (&zr)[8], const float (&zi)[8],
                                      int u)
{
    const int rev3t[8] = { 0, 4, 2, 6, 1, 5, 3, 7 };
    #pragma unroll
    for (int j = 0; j < 8; ++j) Z[80 * rev3t[j] + u] = make_float2(zr[j], zi[j]);
}

__device__ __forceinline__ void rdEx(const float2* Z, int L, float4 (&q)[4])
{
    q[0] = *(const float4*)&Z[10 * L + 0];
    q[1] = *(const float4*)&Z[10 * L + 2];
    q[2] = *(const float4*)&Z[10 * L + 4];
    q[3] = *(const float4*)&Z[10 * L + 6];
}

__device__ __forceinline__ void rdMag(const float2* Z, int L,
    float4 (&aq)[4], float4 (&tq)[4], float2& b0)
{
    aq[0] = *(const float4*)&Z[10 * L + 0];
    aq[1] = *(const float4*)&Z[10 * L + 2];
    aq[2] = *(const float4*)&Z[10 * L + 4];
    aq[3] = *(const float4*)&Z[10 * L + 6];
    tq[0] = *(const float4*)&Z[630 - 10 * L + 0];   // i=0,1 (j=8,7)
    tq[1] = *(const float4*)&Z[630 - 10 * L + 2];   // i=2,3 (j=6,5)
    tq[2] = *(const float4*)&Z[630 - 10 * L + 4];   // i=4,5 (j=4,3)
    tq[3] = *(const float4*)&Z[630 - 10 * L + 6];   // i=6,7 (j=2,1)
    b0    = Z[640 - 10 * L];                        // j=0 (garbage if L==0)
}

// r14: branchless general path + single lane-0 fixup; hw sqrt.
// r15: twS computed on the fly (rev = -L/128 - j/1024, exact) -> frees 16
// always-live VGPRs; 16 quarter-rate TRANS ops/frame, issue-cheap.
__device__ __forceinline__ void magPhase(const float4 (&aq)[4], const float4 (&tq)[4],
    const float2 b0, const int L, uint4& mgpo, float& m512o)
{
    float Ax[8], Ay[8], Bx[8], By[8];
    Ax[0] = aq[0].x; Ay[0] = aq[0].y; Ax[1] = aq[0].z; Ay[1] = aq[0].w;
    Ax[2] = aq[1].x; Ay[2] = aq[1].y; Ax[3] = aq[1].z; Ay[3] = aq[1].w;
    Ax[4] = aq[2].x; Ay[4] = aq[2].y; Ax[5] = aq[2].z; Ay[5] = aq[2].w;
    Ax[6] = aq[3].x; Ay[6] = aq[3].y; Ax[7] = aq[3].z; Ay[7] = aq[3].w;
    Bx[0] = b0.x;    By[0] = b0.y;
    Bx[7] = tq[0].z; By[7] = tq[0].w;
    Bx[6] = tq[1].x; By[6] = tq[1].y;
    Bx[5] = tq[1].z; By[5] = tq[1].w;
    Bx[4] = tq[2].x; By[4] = tq[2].y;
    Bx[3] = tq[2].z; By[3] = tq[2].w;
    Bx[2] = tq[3].x; By[2] = tq[3].y;
    Bx[1] = tq[3].z; By[1] = tq[3].w;
    const float s0 = -(float)L * INV128;
    float mg[8];
    #pragma unroll
    for (int j = 0; j < 8; ++j) {
        float2 tws = twid(s0 - (float)j * INV1024);   // W^(8L+j)
        float xer = 0.5f * (Ax[j] + Bx[j]), xei = 0.5f * (Ay[j] - By[j]);
        float xo  = 0.5f * (Ay[j] + By[j]), xoi = -0.5f * (Ax[j] - Bx[j]);
        float xr = xer + tws.x * xo - tws.y * xoi;
        float xi = xei + tws.x * xoi + tws.y * xo;
        mg[j] = __builtin_amdgcn_sqrtf(xr * xr + xi * xi);
    }
    if (L == 0) {                        // bin k=0: X[0] = sum, m512 = alt-sum
        mg[0]  = fabsf(Ax[0] + Ay[0]);
        m512o  = fabsf(Ax[0] - Ay[0]);
    }
    mgpo.x = pk_f16(mg[0], mg[1]);
    mgpo.y = pk_f16(mg[2], mg[3]);
    mgpo.z = pk_f16(mg[4], mg[5]);
    mgpo.w = pk_f16(mg[6], mg[7]);
}

// ---------------------------------------------------------------------------
// Stage 1: 16 frames per block (4 waves x 2 PAIRS of pipelined FFTs).
// r10: slot(x) = x + 2*(x>>3) padding; writes <=2-way-conflict-free, reads
// lane-contiguous 16B-aligned ds_read_b128.
// r11/r12: DS-only sched_barrier fences + sample prefetch, plain bounds.
// r13: 2-frame software pipeline per wave, single Z buffer (in-order DS).
// r14: rolled pair loop (I$), branchless mag, hw sqrt.
// r15: VGPR diet for occupancy. The kernel is stall-bound (VALU 44%, DS 25%,
// HBM 6%) with ~1.5-2 waves/SIMD; occupancy has tracked VGPR across rounds.
// Freed: 36 always-live twiddle-table regs (on-the-fly v_sin/v_cos in
// revolutions, pow2-exact args) + 20 prefetch regs (next-pair samples now
// reload xA/xB IN PLACE right after their last use; VMEM crosses the DS
// fences, latency covered by ~2500 cy of remaining pair compute).
// ---------------------------------------------------------------------------
__global__ __launch_bounds__(256) void mfcc_stage1(
    const float* __restrict__ wave, const float* __restrict__ ws,
    float* __restrict__ out)
{
    // LDS: float2 Z[4][640] (20480 B) overlaid by f16 mag[16][552] (17664 B);
    // lm[16][40] f16 (1280 B) lives at +17664 (dead space above mag tile).
    // +16 B guard: lane0's don't-care Z[640-0] read from wave 3.
    __shared__ __align__(16) char smem[4 * 640 * 8 + 16];
    char* smemc = smem;
    _Float16* lm = (_Float16*)(smem + 16 * 1104);    // [16][40] f16 @ 17664

    const int tid = threadIdx.x;
    const int wv  = tid >> 6;
    const int L   = tid & 63;
    const int s   = L & 7;
    const int a   = L >> 3;

    float2* Z = (float2*)smem + wv * 640;            // wave-private FFT buffer
    const float2* R   = (const float2*)(ws + WS_R);
    const float2* win = (const float2*)(ws + WS_WIN);

    // ---- only the hottest tables stay in registers (twA: 4 pairs/frame in
    // phaseI; winv: 10 values/frame). Everything else is computed on the fly.
    float2 twA[4], winv[5];
    #pragma unroll
    for (int j = 0; j < 4; ++j) twA[j] = R[2 * (L + 64 * j)];
    #pragma unroll
    for (int j = 0; j < 5; ++j) winv[j] = win[L + 64 * j];

    // bit-reverse slot base for the final write, loop-invariant
    const int r6 = (int)(__brev((unsigned)L) >> 26);
    const int u  = r6 + 2 * (r6 >> 3);

    // per-frame packed f16 magnitudes, rotated through named regs (no dynamic
    // indexing -> no scratch). After 2 iterations: mgp0..3 = frames 0..3.
    uint4 mgp0, mgp1, mgp2, mgp3;
    float m5120 = 0.0f, m5121 = 0.0f, m5122 = 0.0f, m5123 = 0.0f;

    const int fbase = blockIdx.x * 16 + wv * 4;

    // prefetch pair 0's samples
    float2 xA[5], xB[5];
    ldFrame(xA, wave, fbase + 0, L);
    ldFrame(xB, wave, fbase + 1, L);

    #pragma unroll 1
    for (int p = 0; p < 2; ++p) {
        float zrA[8], ziA[8], zrB[8], ziB[8];
        float4 qA[4], qB[4];

        // ---- exchange-1 round ----
        phaseI(zrA, ziA, xA, winv, twA, L);
        FFT_SB();
        wrEx1(Z, zrA, ziA, s, a);
        FFT_SB();
        rdEx(Z, L, qA);                 // rd1A: latency covered by phaseI(B)
        FFT_SB();
        phaseI(zrB, ziB, xB, winv, twA, L);
        wrEx1(Z, zrB, ziB, s, a);       // DS order: after rd1A ✓
        FFT_SB();
        // r15: next pair's samples reload xA/xB IN PLACE (last use was just
        // above); results not needed until next iteration's phaseI.
        if (p == 0) {
            ldFrame(xA, wave, fbase + 2, L);
            ldFrame(xB, wave, fbase + 3, L);
        }
        rdEx(Z, L, qB);                 // rd1B: covered by phaseII(A)
        FFT_SB();

        // ---- exchange-2 round ----
        phaseII(zrA, ziA, qA, s);
        wrEx2(Z, zrA, ziA, s, a);       // after rd1B ✓
        FFT_SB();
        rdEx(Z, L, qA);                 // rd2A: covered by phaseII(B)
        FFT_SB();
        phaseII(zrB, ziB, qB, s);
        wrEx2(Z, zrB, ziB, s, a);       // after rd2A ✓
        FFT_SB();
        rdEx(Z, L, qB);                 // rd2B: covered by phaseIII(A)
        FFT_SB();

        // ---- final bit-reverse round + real-split reads ----
        phaseIII(zrA, ziA, qA);
        wrEx3(Z, zrA, ziA, u);          // after rd2B ✓
        FFT_SB();
        float4 aqA[4], tqA[4]; float2 b0A;
        rdMag(Z, L, aqA, tqA, b0A);     // rd3A: covered by phaseIII(B)
        FFT_SB();
        phaseIII(zrB, ziB, qB);
        wrEx3(Z, zrB, ziB, u);          // after rd3A ✓
        FFT_SB();
        float4 aqB[4], tqB[4]; float2 b0B;
        rdMag(Z, L, aqB, tqB, b0B);     // rd3B: covered by magPhase(A)
        FFT_SB();

        // ---- magnitudes ----
        uint4 mgA, mgB;
        float mA = 0.0f, mB = 0.0f;
        magPhase(aqA, tqA, b0A, L, mgA, mA);
        magPhase(aqB, tqB, b0B, L, mgB, mB);
        FFT_SB();   // Z reads ordered before next pair's writes

        // rotate the result queue (static register moves)
        mgp0 = mgp2;  mgp1 = mgp3;  mgp2 = mgA;  mgp3 = mgB;
        m5120 = m5122; m5121 = m5123; m5122 = mA; m5123 = mB;
    }

    // ---- all FFTs done: overlay mag tile [16][552] f16 onto smem ----
    __syncthreads();
    {
        const int row = wv * 4;
        *(uint4*)(smemc + (row + 0) * 1104 + 16 * L) = mgp0;
        *(uint4*)(smemc + (row + 1) * 1104 + 16 * L) = mgp1;
        *(uint4*)(smemc + (row + 2) * 1104 + 16 * L) = mgp2;
        *(uint4*)(smemc + (row + 3) * 1104 + 16 * L) = mgp3;
        if (L < 20) {   // zero pad bins [512..552), bin 512 = m512
            unsigned v0 = (L == 0) ? pk_f16(m5120, 0.0f) : 0u;
            unsigned v1 = (L == 0) ? pk_f16(m5121, 0.0f) : 0u;
            unsigned v2 = (L == 0) ? pk_f16(m5122, 0.0f) : 0u;
            unsigned v3 = (L == 0) ? pk_f16(m5123, 0.0f) : 0u;
            *(unsigned*)(smemc + (row + 0) * 1104 + 1024 + 4 * L) = v0;
            *(unsigned*)(smemc + (row + 1) * 1104 + 1024 + 4 * L) = v1;
            *(unsigned*)(smemc + (row + 2) * 1104 + 1024 + 4 * L) = v2;
            *(unsigned*)(smemc + (row + 3) * 1104 + 1024 + 4 * L) = v3;
        }
    }
    __syncthreads();

    // ---- mel projection: D[16 frames][16 mels] per wave, K = 544 ----
    if (wv < 3) {
        const int nl = L & 15, q = L >> 4;
        const char* ap = smemc + nl * 1104 + q * 16;                // A: frame rows
        const _Float16* btp = (const _Float16*)(ws + WS_BT)
                              + (size_t)(wv * 16 + nl) * 544 + q * 8;
        f32x4 acc = {0.0f, 0.0f, 0.0f, 0.0f};
        #pragma unroll
        for (int kk = 0; kk < 17; ++kk) {
            half8 av = *(const half8*)(ap + kk * 64);
            half8 bv = *(const half8*)(btp + kk * 32);
            acc = __builtin_amdgcn_mfma_f32_16x16x32_f16(av, bv, acc, 0, 0, 0);
        }
        const int mel = wv * 16 + nl;
        if (mel < NMEL) {
            #pragma unroll
            for (int r = 0; r < 4; ++r) {
                int fl = q * 4 + r;                 // C/D: row=(lane>>4)*4+r
                lm[fl * NMEL + mel] = (_Float16)__logf(acc[r] + 1e-6f);
            }
        }
    }
    __syncthreads();

    // ---- DCT + scale + lifter, fp32: 208 threads = 16 frames x 13 ceps ----
    if (tid < 16 * NCEP) {
        const int fl = tid / NCEP, c = tid - fl * NCEP;
        float acc = 0.0f;
        #pragma unroll
        for (int m = 0; m < NMEL; ++m)
            acc += (float)lm[fl * NMEL + m] * ws[WS_DT + m * 13 + c];
        out[(size_t)(blockIdx.x * 16 + fl) * (3 * NCEP) + c] = acc;
    }
}

// ---------------------------------------------------------------------------
// Stage 2: per-batch deltas.
// ---------------------------------------------------------------------------
__global__ __launch_bounds__(128) void mfcc_stage2(float* __restrict__ out)
{
    __shared__ float x [NFRAME * NCEP];
    __shared__ float d1[NFRAME * NCEP];

    const int b = blockIdx.x;
    const int tid = threadIdx.x;
    const int TC = NFRAME * NCEP;

    for (int i = tid; i < TC; i += 128) {
        const int t = i / NCEP, c = i - t * NCEP;
        x[i] = out[((size_t)b * NFRAME + t) * (3 * NCEP) + c];
    }
    __syncthreads();

    for (int i = tid; i < TC; i += 128) {
        const int t = i / NCEP, c = i - t * NCEP;
        float acc = 0.0f;
        #pragma unroll
        for (int k = -2; k <= 2; ++k) {
            if (k == 0) continue;
            int tt = t + k;
            tt = tt < 0 ? 0 : (tt > NFRAME - 1 ? NFRAME - 1 : tt);
            acc += (float)k * x[tt * NCEP + c];
        }
        d1[i] = acc * 0.1f;
    }
    __syncthreads();

    for (int i = tid; i < TC; i += 128) {
        const int t = i / NCEP, c = i - t * NCEP;
        float acc = 0.0f;
        #pragma unroll
        for (int k = -2; k <= 2; ++k) {
            if (k == 0) continue;
            int tt = t + k;
            tt = tt < 0 ? 0 : (tt > NFRAME - 1 ? NFRAME - 1 : tt);
            acc += (float)k * d1[tt * NCEP + c];
        }
        const size_t base = ((size_t)b * NFRAME + t) * (3 * NCEP);
        out[base +     NCEP + c] = d1[i];
        out[base + 2 * NCEP + c] = acc * 0.1f;
    }
}

extern "C" void kernel_launch(void* const* d_in, const int* in_sizes, int n_in,
                              void* d_out, int out_size, void* d_ws, size_t ws_size,
                              hipStream_t stream)
{
    const float* wave   = (const float*)d_in[0];   // [1024][16000] f32
    const float* mel_fb = (const float*)d_in[1];   // [513][40] f32
    float* out = (float*)d_out;                    // [1024][49][39][1] f32
    float* ws  = (float*)d_ws;

    mfcc_prep<<<64, 256, 0, stream>>>(mel_fb, ws);
    mfcc_stage1<<<(BATCH * NFRAME) / 16, 256, 0, stream>>>(wave, ws, out);
    mfcc_stage2<<<BATCH, 128, 0, stream>>>(out);
}